// Round 1
// baseline (949.499 us; speedup 1.0000x reference)
//
#include <hip/hip_runtime.h>
#include <hip/hip_bf16.h>

#define NN 50000
#define HH 128
#define NHEAD 4
#define HD 32
#define EE 800000
#define LN_EPS 1e-5f

// ---------------- index dtype probe + conversion ----------------
// If edge_index arrived as int64 (little-endian, values < 50000), every odd
// int32 word is 0. If int32, odd words are random node ids (P(all 64 == 0) ~ 0).
__global__ void detect_idx_kernel(const unsigned int* __restrict__ buf, int* __restrict__ flag) {
    if (blockIdx.x == 0 && threadIdx.x == 0) {
        int is64 = 1;
        for (int i = 0; i < 64; ++i) {
            if (buf[2 * i + 1] != 0u) { is64 = 0; break; }
        }
        *flag = is64;
    }
}

__global__ void convert_idx_kernel(const void* __restrict__ ei, const int* __restrict__ flag,
                                   int* __restrict__ rowi, int* __restrict__ coli) {
    int i = blockIdx.x * blockDim.x + threadIdx.x;
    if (i >= EE) return;
    if (*flag) {
        const long long* p = (const long long*)ei;
        rowi[i] = (int)p[i];
        coli[i] = (int)p[EE + i];
    } else {
        const int* p = (const int*)ei;
        rowi[i] = p[i];
        coli[i] = p[EE + i];
    }
}

// ---------------- QKV projection ----------------
// block = 128 threads (one output column each), 16 rows per block.
// LDS x-tile read as broadcast (same address across lanes -> no bank conflict).
__global__ void qkv_kernel(const float* __restrict__ x,
                           const float* __restrict__ Wq, const float* __restrict__ bq,
                           const float* __restrict__ Wk, const float* __restrict__ bk,
                           const float* __restrict__ Wv, const float* __restrict__ bv,
                           float* __restrict__ Q, float* __restrict__ K, float* __restrict__ V) {
    __shared__ float xs[16][129];
    const int r0 = blockIdx.x * 16;
    const int c = threadIdx.x;

    #pragma unroll
    for (int r = 0; r < 16; ++r)
        xs[r][c] = x[(size_t)(r0 + r) * HH + c];
    __syncthreads();

    const float* Ws[3] = {Wq, Wk, Wv};
    const float* bs[3] = {bq, bk, bv};
    float* Os[3] = {Q, K, V};

    for (int mtx = 0; mtx < 3; ++mtx) {
        const float* __restrict__ W = Ws[mtx];
        float acc[16];
        #pragma unroll
        for (int r = 0; r < 16; ++r) acc[r] = 0.f;
        for (int k = 0; k < HH; ++k) {
            float w = W[k * HH + c];
            #pragma unroll
            for (int r = 0; r < 16; ++r) acc[r] += xs[r][k] * w;
        }
        float b = bs[mtx][c];
        float* __restrict__ O = Os[mtx];
        #pragma unroll
        for (int r = 0; r < 16; ++r)
            O[(size_t)(r0 + r) * HH + c] = acc[r] + b;
    }
}

// ---------------- edge scores + segment max ----------------
// one thread per (edge, head); monotone uint encoding for f32 atomicMax
__device__ __forceinline__ unsigned int f32_to_ord(float s) {
    unsigned int u = __float_as_uint(s);
    return (u & 0x80000000u) ? ~u : (u | 0x80000000u);
}
__device__ __forceinline__ float ord_to_f32(unsigned int u) {
    return (u & 0x80000000u) ? __uint_as_float(u ^ 0x80000000u) : __uint_as_float(~u);
}

__global__ void score_kernel(const float* __restrict__ Q, const float* __restrict__ K,
                             const int* __restrict__ rowi, const int* __restrict__ coli,
                             float* __restrict__ scores, unsigned int* __restrict__ m_u) {
    int t = blockIdx.x * blockDim.x + threadIdx.x;
    if (t >= EE * NHEAD) return;
    int e = t >> 2, h = t & 3;
    int r = rowi[e], cs = coli[e];
    const float4* qp = (const float4*)(Q + (size_t)r * HH + h * HD);
    const float4* kp = (const float4*)(K + (size_t)cs * HH + h * HD);
    float acc = 0.f;
    #pragma unroll
    for (int i = 0; i < 8; ++i) {
        float4 a = qp[i], b = kp[i];
        acc += a.x * b.x + a.y * b.y + a.z * b.z + a.w * b.w;
    }
    float s = acc * 0.17677669529663689f;  // 1/sqrt(32)
    scores[t] = s;
    atomicMax(&m_u[r * NHEAD + h], f32_to_ord(s));
}

// ---------------- exp + denom + weighted scatter (unnormalized) ----------------
// 128 threads per edge -> coalesced V row read; agg = sum(e * V), denom = sum(e)
__global__ void agg_kernel(const float* __restrict__ V, const float* __restrict__ scores,
                           const unsigned int* __restrict__ m_u,
                           const int* __restrict__ rowi, const int* __restrict__ coli,
                           float* __restrict__ denom, float* __restrict__ agg) {
    long long t = (long long)blockIdx.x * blockDim.x + threadIdx.x;
    if (t >= (long long)EE * HH) return;
    int e = (int)(t >> 7);
    int d = (int)(t & 127);
    int h = d >> 5;
    int r = rowi[e], cs = coli[e];
    float s = scores[e * NHEAD + h];
    float m = ord_to_f32(m_u[r * NHEAD + h]);
    float ev = __expf(s - m);
    if ((d & 31) == 0) atomicAdd(&denom[r * NHEAD + h], ev);
    atomicAdd(&agg[(size_t)r * HH + d], ev * V[(size_t)cs * HH + d]);
}

// ---------------- MLP1 (concat GEMM) + ReLU + LayerNorm ----------------
__global__ void mlp1_kernel(const float* __restrict__ x, const float* __restrict__ agg,
                            const float* __restrict__ denom,
                            const float* __restrict__ W1, const float* __restrict__ b1,
                            const float* __restrict__ ln_g, const float* __restrict__ ln_b,
                            float* __restrict__ hout) {
    __shared__ float as[16][257];
    __shared__ float hs[16][129];
    __shared__ float psum[16][8], psq[16][8];
    __shared__ float mu_s[16], rs_s[16];
    const int r0 = blockIdx.x * 16;
    const int c = threadIdx.x;

    #pragma unroll
    for (int r = 0; r < 16; ++r) {
        int gr = r0 + r;
        as[r][c] = x[(size_t)gr * HH + c];
        float av = agg[(size_t)gr * HH + c];
        float dn = denom[gr * NHEAD + (c >> 5)];
        as[r][HH + c] = (dn > 0.f) ? av / dn : 0.f;
    }
    __syncthreads();

    float acc[16];
    #pragma unroll
    for (int r = 0; r < 16; ++r) acc[r] = 0.f;
    for (int k = 0; k < 2 * HH; ++k) {
        float w = W1[k * HH + c];
        #pragma unroll
        for (int r = 0; r < 16; ++r) acc[r] += as[r][k] * w;
    }
    float b = b1[c];
    #pragma unroll
    for (int r = 0; r < 16; ++r) {
        float v = acc[r] + b;
        hs[r][c] = v > 0.f ? v : 0.f;
    }
    __syncthreads();

    {   // per-row mean / sumsq: 8 segments of 16 columns per row
        int r = c & 15, seg = c >> 4;
        float s = 0.f, sq = 0.f;
        #pragma unroll
        for (int j = 0; j < 16; ++j) {
            float v = hs[r][seg * 16 + j];
            s += v; sq += v * v;
        }
        psum[r][seg] = s; psq[r][seg] = sq;
    }
    __syncthreads();
    if (c < 16) {
        float s = 0.f, sq = 0.f;
        #pragma unroll
        for (int j = 0; j < 8; ++j) { s += psum[c][j]; sq += psq[c][j]; }
        float mu = s * (1.f / 128.f);
        float var = sq * (1.f / 128.f) - mu * mu;
        mu_s[c] = mu;
        rs_s[c] = rsqrtf(var + LN_EPS);
    }
    __syncthreads();

    float g = ln_g[c], bb = ln_b[c];
    #pragma unroll
    for (int r = 0; r < 16; ++r)
        hout[(size_t)(r0 + r) * HH + c] = (hs[r][c] - mu_s[r]) * rs_s[r] * g + bb;
}

// ---------------- MLP2 + residual ----------------
__global__ void mlp2_kernel(const float* __restrict__ h, const float* __restrict__ x,
                            const float* __restrict__ W2, const float* __restrict__ b2,
                            float* __restrict__ out) {
    __shared__ float as[16][129];
    const int r0 = blockIdx.x * 16;
    const int c = threadIdx.x;
    #pragma unroll
    for (int r = 0; r < 16; ++r)
        as[r][c] = h[(size_t)(r0 + r) * HH + c];
    __syncthreads();
    float acc[16];
    #pragma unroll
    for (int r = 0; r < 16; ++r) acc[r] = 0.f;
    for (int k = 0; k < HH; ++k) {
        float w = W2[k * HH + c];
        #pragma unroll
        for (int r = 0; r < 16; ++r) acc[r] += as[r][k] * w;
    }
    float b = b2[c];
    #pragma unroll
    for (int r = 0; r < 16; ++r) {
        size_t idx = (size_t)(r0 + r) * HH + c;
        out[idx] = acc[r] + b + x[idx];
    }
}

extern "C" void kernel_launch(void* const* d_in, const int* in_sizes, int n_in,
                              void* d_out, int out_size, void* d_ws, size_t ws_size,
                              hipStream_t stream) {
    const float* x    = (const float*)d_in[0];
    const void*  ei   = d_in[1];
    const float* Wq   = (const float*)d_in[2];
    const float* bq   = (const float*)d_in[3];
    const float* Wk   = (const float*)d_in[4];
    const float* bk   = (const float*)d_in[5];
    const float* Wv   = (const float*)d_in[6];
    const float* bv   = (const float*)d_in[7];
    const float* W1   = (const float*)d_in[8];
    const float* b1   = (const float*)d_in[9];
    const float* ln_g = (const float*)d_in[10];
    const float* ln_b = (const float*)d_in[11];
    const float* W2   = (const float*)d_in[12];
    const float* b2   = (const float*)d_in[13];
    float* out = (float*)d_out;

    // workspace layout (256B aligned)
    char* ws = (char*)d_ws;
    size_t off = 0;
    auto alloc = [&](size_t bytes) {
        size_t o = off;
        off = (off + bytes + 255) & ~(size_t)255;
        return o;
    };
    size_t flag_o   = alloc(sizeof(int));
    size_t rowi_o   = alloc((size_t)EE * sizeof(int));
    size_t coli_o   = alloc((size_t)EE * sizeof(int));
    size_t scores_o = alloc((size_t)EE * NHEAD * sizeof(float));
    size_t Q_o      = alloc((size_t)NN * HH * sizeof(float));
    size_t K_o      = alloc((size_t)NN * HH * sizeof(float));
    size_t V_o      = alloc((size_t)NN * HH * sizeof(float));
    size_t m_o      = alloc((size_t)NN * NHEAD * sizeof(unsigned int));
    size_t den_o    = alloc((size_t)NN * NHEAD * sizeof(float));
    size_t agg_o    = alloc((size_t)NN * HH * sizeof(float));
    // h reuses Q's buffer (Q dead after score_kernel)
    size_t h_o = Q_o;

    int*          rowi   = (int*)(ws + rowi_o);
    int*          coli   = (int*)(ws + coli_o);
    float*        scores = (float*)(ws + scores_o);
    float*        Q      = (float*)(ws + Q_o);
    float*        K      = (float*)(ws + K_o);
    float*        V      = (float*)(ws + V_o);
    unsigned int* m_u    = (unsigned int*)(ws + m_o);
    float*        den    = (float*)(ws + den_o);
    float*        agg    = (float*)(ws + agg_o);
    float*        h      = (float*)(ws + h_o);
    int*          flag   = (int*)(ws + flag_o);

    // zero the accumulators (m_u .. agg are contiguous in layout)
    hipMemsetAsync(ws + m_o, 0, (agg_o + (size_t)NN * HH * sizeof(float)) - m_o, stream);

    detect_idx_kernel<<<1, 64, 0, stream>>>((const unsigned int*)ei, flag);
    convert_idx_kernel<<<(EE + 255) / 256, 256, 0, stream>>>(ei, flag, rowi, coli);

    qkv_kernel<<<NN / 16, 128, 0, stream>>>(x, Wq, bq, Wk, bk, Wv, bv, Q, K, V);

    score_kernel<<<(EE * NHEAD) / 256, 256, 0, stream>>>(Q, K, rowi, coli, scores, m_u);

    agg_kernel<<<(int)(((long long)EE * HH) / 256), 256, 0, stream>>>(
        V, scores, m_u, rowi, coli, den, agg);

    mlp1_kernel<<<NN / 16, 128, 0, stream>>>(x, agg, den, W1, b1, ln_g, ln_b, h);

    mlp2_kernel<<<NN / 16, 128, 0, stream>>>(h, x, W2, b2, out);
}

// Round 2
// 651.179 us; speedup vs baseline: 1.4581x; 1.4581x over previous
//
#include <hip/hip_runtime.h>
#include <hip/hip_bf16.h>

#define NN 50000
#define HH 128
#define NHEAD 4
#define HD 32
#define EE 800000
#define LN_EPS 1e-5f

// ---------------- index dtype probe ----------------
__global__ void detect_idx_kernel(const unsigned int* __restrict__ buf, int* __restrict__ flag) {
    if (blockIdx.x == 0 && threadIdx.x == 0) {
        int is64 = 1;
        for (int i = 0; i < 64; ++i) {
            if (buf[2 * i + 1] != 0u) { is64 = 0; break; }
        }
        *flag = is64;
    }
}

// convert edge index to int32 row/col AND histogram destination degrees
__global__ void convert_hist_kernel(const void* __restrict__ ei, const int* __restrict__ flag,
                                    int* __restrict__ rowi, int* __restrict__ coli,
                                    int* __restrict__ deg) {
    int i = blockIdx.x * blockDim.x + threadIdx.x;
    if (i >= EE) return;
    int r, c;
    if (*flag) {
        const long long* p = (const long long*)ei;
        r = (int)p[i];
        c = (int)p[EE + i];
    } else {
        const int* p = (const int*)ei;
        r = p[i];
        c = p[EE + i];
    }
    rowi[i] = r;
    coli[i] = c;
    atomicAdd(&deg[r], 1);
}

// ---------------- exclusive scan over 50k degrees (single block) ----------------
__global__ __launch_bounds__(1024) void scan_kernel(const int* __restrict__ deg,
                                                    int* __restrict__ row_start,
                                                    int* __restrict__ cursor) {
    __shared__ int buf[2][1024];
    const int t = threadIdx.x;
    const int CH = (NN + 1023) / 1024;  // 49
    const int lo = t * CH;
    const int hi = (lo + CH < NN) ? lo + CH : NN;
    int sum = 0;
    for (int i = lo; i < hi; ++i) sum += deg[i];
    buf[0][t] = sum;
    __syncthreads();
    int src = 0;
    for (int ofs = 1; ofs < 1024; ofs <<= 1) {
        int v = buf[src][t];
        if (t >= ofs) v += buf[src][t - ofs];
        buf[src ^ 1][t] = v;
        __syncthreads();
        src ^= 1;
    }
    int excl = (t == 0) ? 0 : buf[src][t - 1];
    int run = excl;
    for (int i = lo; i < hi; ++i) {
        row_start[i] = run;
        cursor[i] = run;
        run += deg[i];
    }
    if (hi == NN) row_start[NN] = run;  // all qualifying threads write the same total
}

// scatter col ids into CSR order
__global__ void scatter_kernel(const int* __restrict__ rowi, const int* __restrict__ coli,
                               int* __restrict__ cursor, int* __restrict__ colS) {
    int i = blockIdx.x * blockDim.x + threadIdx.x;
    if (i >= EE) return;
    int pos = atomicAdd(&cursor[rowi[i]], 1);
    colS[pos] = coli[i];
}

// ---------------- QKV projection ----------------
__global__ void qkv_kernel(const float* __restrict__ x,
                           const float* __restrict__ Wq, const float* __restrict__ bq,
                           const float* __restrict__ Wk, const float* __restrict__ bk,
                           const float* __restrict__ Wv, const float* __restrict__ bv,
                           float* __restrict__ Q, float* __restrict__ K, float* __restrict__ V) {
    __shared__ float xs[16][129];
    const int r0 = blockIdx.x * 16;
    const int c = threadIdx.x;

    #pragma unroll
    for (int r = 0; r < 16; ++r)
        xs[r][c] = x[(size_t)(r0 + r) * HH + c];
    __syncthreads();

    const float* Ws[3] = {Wq, Wk, Wv};
    const float* bs[3] = {bq, bk, bv};
    float* Os[3] = {Q, K, V};

    for (int mtx = 0; mtx < 3; ++mtx) {
        const float* __restrict__ W = Ws[mtx];
        float acc[16];
        #pragma unroll
        for (int r = 0; r < 16; ++r) acc[r] = 0.f;
        for (int k = 0; k < HH; ++k) {
            float w = W[k * HH + c];
            #pragma unroll
            for (int r = 0; r < 16; ++r) acc[r] += xs[r][k] * w;
        }
        float b = bs[mtx][c];
        float* __restrict__ O = Os[mtx];
        #pragma unroll
        for (int r = 0; r < 16; ++r)
            O[(size_t)(r0 + r) * HH + c] = acc[r] + b;
    }
}

// ---------------- fused per-node attention (online softmax, no atomics) ----------------
// one block of 128 threads per node; thread d owns output dim d (head = d>>5)
__global__ void attn_kernel(const float* __restrict__ Q, const float* __restrict__ K,
                            const float* __restrict__ V,
                            const int* __restrict__ row_start, const int* __restrict__ colS,
                            float* __restrict__ agg) {
    const int i = blockIdx.x;
    const int d = threadIdx.x;
    const float q = Q[(size_t)i * HH + d];
    const int e0 = row_start[i], e1 = row_start[i + 1];

    float m = -INFINITY, l = 0.f, acc = 0.f;
    for (int e = e0; e < e1; ++e) {
        int c = colS[e];
        float p = q * K[(size_t)c * HH + d];
        // sum over the 32 lanes of this head group
        p += __shfl_xor(p, 16, 32);
        p += __shfl_xor(p, 8, 32);
        p += __shfl_xor(p, 4, 32);
        p += __shfl_xor(p, 2, 32);
        p += __shfl_xor(p, 1, 32);
        float s = p * 0.17677669529663689f;  // 1/sqrt(32)
        float mn = fmaxf(m, s);
        float fac = __expf(m - mn);  // first iter: exp(-inf) = 0
        float ev = __expf(s - mn);
        l = l * fac + ev;
        acc = acc * fac + ev * V[(size_t)c * HH + d];
        m = mn;
    }
    agg[(size_t)i * HH + d] = (l > 0.f) ? acc / l : 0.f;
}

// ---------------- MLP1 (concat GEMM) + ReLU + LayerNorm ----------------
__global__ void mlp1_kernel(const float* __restrict__ x, const float* __restrict__ agg,
                            const float* __restrict__ W1, const float* __restrict__ b1,
                            const float* __restrict__ ln_g, const float* __restrict__ ln_b,
                            float* __restrict__ hout) {
    __shared__ float as[16][257];
    __shared__ float hs[16][129];
    __shared__ float psum[16][8], psq[16][8];
    __shared__ float mu_s[16], rs_s[16];
    const int r0 = blockIdx.x * 16;
    const int c = threadIdx.x;

    #pragma unroll
    for (int r = 0; r < 16; ++r) {
        int gr = r0 + r;
        as[r][c] = x[(size_t)gr * HH + c];
        as[r][HH + c] = agg[(size_t)gr * HH + c];
    }
    __syncthreads();

    float acc[16];
    #pragma unroll
    for (int r = 0; r < 16; ++r) acc[r] = 0.f;
    for (int k = 0; k < 2 * HH; ++k) {
        float w = W1[k * HH + c];
        #pragma unroll
        for (int r = 0; r < 16; ++r) acc[r] += as[r][k] * w;
    }
    float b = b1[c];
    #pragma unroll
    for (int r = 0; r < 16; ++r) {
        float v = acc[r] + b;
        hs[r][c] = v > 0.f ? v : 0.f;
    }
    __syncthreads();

    {   // per-row mean / sumsq: 8 segments of 16 columns per row
        int r = c & 15, seg = c >> 4;
        float s = 0.f, sq = 0.f;
        #pragma unroll
        for (int j = 0; j < 16; ++j) {
            float v = hs[r][seg * 16 + j];
            s += v; sq += v * v;
        }
        psum[r][seg] = s; psq[r][seg] = sq;
    }
    __syncthreads();
    if (c < 16) {
        float s = 0.f, sq = 0.f;
        #pragma unroll
        for (int j = 0; j < 8; ++j) { s += psum[c][j]; sq += psq[c][j]; }
        float mu = s * (1.f / 128.f);
        float var = sq * (1.f / 128.f) - mu * mu;
        mu_s[c] = mu;
        rs_s[c] = rsqrtf(var + LN_EPS);
    }
    __syncthreads();

    float g = ln_g[c], bb = ln_b[c];
    #pragma unroll
    for (int r = 0; r < 16; ++r)
        hout[(size_t)(r0 + r) * HH + c] = (hs[r][c] - mu_s[r]) * rs_s[r] * g + bb;
}

// ---------------- MLP2 + residual ----------------
__global__ void mlp2_kernel(const float* __restrict__ h, const float* __restrict__ x,
                            const float* __restrict__ W2, const float* __restrict__ b2,
                            float* __restrict__ out) {
    __shared__ float as[16][129];
    const int r0 = blockIdx.x * 16;
    const int c = threadIdx.x;
    #pragma unroll
    for (int r = 0; r < 16; ++r)
        as[r][c] = h[(size_t)(r0 + r) * HH + c];
    __syncthreads();
    float acc[16];
    #pragma unroll
    for (int r = 0; r < 16; ++r) acc[r] = 0.f;
    for (int k = 0; k < HH; ++k) {
        float w = W2[k * HH + c];
        #pragma unroll
        for (int r = 0; r < 16; ++r) acc[r] += as[r][k] * w;
    }
    float b = b2[c];
    #pragma unroll
    for (int r = 0; r < 16; ++r) {
        size_t idx = (size_t)(r0 + r) * HH + c;
        out[idx] = acc[r] + b + x[idx];
    }
}

extern "C" void kernel_launch(void* const* d_in, const int* in_sizes, int n_in,
                              void* d_out, int out_size, void* d_ws, size_t ws_size,
                              hipStream_t stream) {
    const float* x    = (const float*)d_in[0];
    const void*  ei   = d_in[1];
    const float* Wq   = (const float*)d_in[2];
    const float* bq   = (const float*)d_in[3];
    const float* Wk   = (const float*)d_in[4];
    const float* bk   = (const float*)d_in[5];
    const float* Wv   = (const float*)d_in[6];
    const float* bv   = (const float*)d_in[7];
    const float* W1   = (const float*)d_in[8];
    const float* b1   = (const float*)d_in[9];
    const float* ln_g = (const float*)d_in[10];
    const float* ln_b = (const float*)d_in[11];
    const float* W2   = (const float*)d_in[12];
    const float* b2   = (const float*)d_in[13];
    float* out = (float*)d_out;

    // workspace layout (256B aligned)
    char* ws = (char*)d_ws;
    size_t off = 0;
    auto alloc = [&](size_t bytes) {
        size_t o = off;
        off = (off + bytes + 255) & ~(size_t)255;
        return o;
    };
    size_t flag_o   = alloc(sizeof(int));
    size_t rowi_o   = alloc((size_t)EE * sizeof(int));
    size_t coli_o   = alloc((size_t)EE * sizeof(int));
    size_t deg_o    = alloc((size_t)NN * sizeof(int));
    size_t cur_o    = alloc((size_t)NN * sizeof(int));
    size_t rs_o     = alloc((size_t)(NN + 1) * sizeof(int));
    size_t colS_o   = alloc((size_t)EE * sizeof(int));
    size_t Q_o      = alloc((size_t)NN * HH * sizeof(float));
    size_t K_o      = alloc((size_t)NN * HH * sizeof(float));
    size_t V_o      = alloc((size_t)NN * HH * sizeof(float));
    size_t agg_o    = alloc((size_t)NN * HH * sizeof(float));
    size_t h_o = Q_o;  // h reuses Q (dead after attn)

    int*   flag   = (int*)(ws + flag_o);
    int*   rowi   = (int*)(ws + rowi_o);
    int*   coli   = (int*)(ws + coli_o);
    int*   deg    = (int*)(ws + deg_o);
    int*   cursor = (int*)(ws + cur_o);
    int*   rstart = (int*)(ws + rs_o);
    int*   colS   = (int*)(ws + colS_o);
    float* Q      = (float*)(ws + Q_o);
    float* K      = (float*)(ws + K_o);
    float* V      = (float*)(ws + V_o);
    float* agg    = (float*)(ws + agg_o);
    float* h      = (float*)(ws + h_o);

    hipMemsetAsync(ws + deg_o, 0, (size_t)NN * sizeof(int), stream);

    detect_idx_kernel<<<1, 64, 0, stream>>>((const unsigned int*)ei, flag);
    convert_hist_kernel<<<(EE + 255) / 256, 256, 0, stream>>>(ei, flag, rowi, coli, deg);
    scan_kernel<<<1, 1024, 0, stream>>>(deg, rstart, cursor);
    scatter_kernel<<<(EE + 255) / 256, 256, 0, stream>>>(rowi, coli, cursor, colS);

    qkv_kernel<<<NN / 16, 128, 0, stream>>>(x, Wq, bq, Wk, bk, Wv, bv, Q, K, V);

    attn_kernel<<<NN, 128, 0, stream>>>(Q, K, V, rstart, colS, agg);

    mlp1_kernel<<<NN / 16, 128, 0, stream>>>(x, agg, W1, b1, ln_g, ln_b, h);

    mlp2_kernel<<<NN / 16, 128, 0, stream>>>(h, x, W2, b2, out);
}

// Round 3
// 405.252 us; speedup vs baseline: 2.3430x; 1.6068x over previous
//
#include <hip/hip_runtime.h>
#include <hip/hip_bf16.h>

#define NN 50000
#define HH 128
#define NHEAD 4
#define HD 32
#define EE 800000
#define LN_EPS 1e-5f
#define ROWS_PAD 50048   // 782 * 64

typedef __bf16 bf16x8 __attribute__((ext_vector_type(8)));
typedef short  s16x8  __attribute__((ext_vector_type(8)));
typedef float  f32x4  __attribute__((ext_vector_type(4)));

__device__ __forceinline__ f32x4 mfma_bf16(s16x8 a, s16x8 b, f32x4 c) {
    return __builtin_amdgcn_mfma_f32_16x16x32_bf16((bf16x8)a, (bf16x8)b, c, 0, 0, 0);
}

__device__ __forceinline__ unsigned short f2bf(float f) {
    union { float f; unsigned int u; } v; v.f = f;
    unsigned int u = v.u + 0x7FFFu + ((v.u >> 16) & 1u);  // RNE
    return (unsigned short)(u >> 16);
}
__device__ __forceinline__ float bf2f(unsigned short h) {
    union { unsigned int u; float f; } v; v.u = ((unsigned int)h) << 16;
    return v.f;
}

// ---------------- index dtype probe ----------------
__global__ void detect_idx_kernel(const unsigned int* __restrict__ buf, int* __restrict__ flag) {
    if (blockIdx.x == 0 && threadIdx.x == 0) {
        int is64 = 1;
        for (int i = 0; i < 64; ++i) {
            if (buf[2 * i + 1] != 0u) { is64 = 0; break; }
        }
        *flag = is64;
    }
}

__global__ void convert_hist_kernel(const void* __restrict__ ei, const int* __restrict__ flag,
                                    int* __restrict__ rowi, int* __restrict__ coli,
                                    int* __restrict__ deg) {
    int i = blockIdx.x * blockDim.x + threadIdx.x;
    if (i >= EE) return;
    int r, c;
    if (*flag) {
        const long long* p = (const long long*)ei;
        r = (int)p[i];
        c = (int)p[EE + i];
    } else {
        const int* p = (const int*)ei;
        r = p[i];
        c = p[EE + i];
    }
    rowi[i] = r;
    coli[i] = c;
    atomicAdd(&deg[r], 1);
}

__global__ __launch_bounds__(1024) void scan_kernel(const int* __restrict__ deg,
                                                    int* __restrict__ row_start,
                                                    int* __restrict__ cursor) {
    __shared__ int buf[2][1024];
    const int t = threadIdx.x;
    const int CH = (NN + 1023) / 1024;  // 49
    const int lo = t * CH;
    const int hi = (lo + CH < NN) ? lo + CH : NN;
    int sum = 0;
    for (int i = lo; i < hi; ++i) sum += deg[i];
    buf[0][t] = sum;
    __syncthreads();
    int src = 0;
    for (int ofs = 1; ofs < 1024; ofs <<= 1) {
        int v = buf[src][t];
        if (t >= ofs) v += buf[src][t - ofs];
        buf[src ^ 1][t] = v;
        __syncthreads();
        src ^= 1;
    }
    int excl = (t == 0) ? 0 : buf[src][t - 1];
    int run = excl;
    for (int i = lo; i < hi; ++i) {
        row_start[i] = run;
        cursor[i] = run;
        run += deg[i];
    }
    if (hi == NN) row_start[NN] = run;
}

__global__ void scatter_kernel(const int* __restrict__ rowi, const int* __restrict__ coli,
                               int* __restrict__ cursor, int* __restrict__ colS) {
    int i = blockIdx.x * blockDim.x + threadIdx.x;
    if (i >= EE) return;
    int pos = atomicAdd(&cursor[rowi[i]], 1);
    colS[pos] = coli[i];
}

// ---------------- pack x (f32 -> bf16, into left half of xa[ROWS_PAD][256]) ----------------
__global__ void pack_x_kernel(const float* __restrict__ x, unsigned short* __restrict__ xa) {
    int t = blockIdx.x * blockDim.x + threadIdx.x;
    if (t >= NN * HH / 4) return;
    int r = t >> 5;          // 32 float4-chunks per row
    int c4 = (t & 31) << 2;
    float4 v = *(const float4*)(x + (size_t)r * HH + c4);
    ushort4 o;
    o.x = f2bf(v.x); o.y = f2bf(v.y); o.z = f2bf(v.z); o.w = f2bf(v.w);
    *(ushort4*)(xa + (size_t)r * 256 + c4) = o;
}

// ---------------- pack weights into MFMA b-fragment order ----------------
// fragment element index: (((ntile*KSTEPS + kk)*64 + lane)*8 + j)
// value = W[kk*32 + (lane>>4)*8 + j][ntile*16 + (lane&15)]
__global__ void pack_w_kernel(const float* __restrict__ Wq, const float* __restrict__ Wk,
                              const float* __restrict__ Wv, const float* __restrict__ W1,
                              const float* __restrict__ W2, unsigned short* __restrict__ wf) {
    int i = blockIdx.x * blockDim.x + threadIdx.x;
    if (i >= 98304) return;
    float val;
    if (i < 49152) {                      // QKV: ntiles=24, ksteps=4, K=128
        int j = i & 7, lane = (i >> 3) & 63, kk = (i >> 9) & 3, nt = i >> 11;
        int k = kk * 32 + (lane >> 4) * 8 + j;
        int n = nt * 16 + (lane & 15);    // 0..383
        const float* W = (n < 128) ? Wq : ((n < 256) ? Wk : Wv);
        val = W[k * HH + (n & 127)];
    } else if (i < 81920) {               // W1: ntiles=8, ksteps=8, K=256
        int local = i - 49152;
        int j = local & 7, lane = (local >> 3) & 63, kk = (local >> 9) & 7, nt = local >> 12;
        int k = kk * 32 + (lane >> 4) * 8 + j;
        int n = nt * 16 + (lane & 15);
        val = W1[k * HH + n];
    } else {                              // W2: ntiles=8, ksteps=4, K=128
        int local = i - 81920;
        int j = local & 7, lane = (local >> 3) & 63, kk = (local >> 9) & 3, nt = local >> 11;
        int k = kk * 32 + (lane >> 4) * 8 + j;
        int n = nt * 16 + (lane & 15);
        val = W2[k * HH + n];
    }
    wf[i] = f2bf(val);
}

// ---------------- QKV GEMM via MFMA: [ROWS_PAD x 384] = xa[:, :128] @ Wqkv ----------------
__global__ __launch_bounds__(256) void gemm_qkv_kernel(
        const unsigned short* __restrict__ xa, const unsigned short* __restrict__ wf,
        const float* __restrict__ bq, const float* __restrict__ bk, const float* __restrict__ bv,
        unsigned short* __restrict__ Qb, unsigned short* __restrict__ Kb,
        unsigned short* __restrict__ Vb) {
    const int wave = threadIdx.x >> 6, lane = threadIdx.x & 63;
    const int row0 = blockIdx.x * 64 + wave * 16;
    const int arow = row0 + (lane & 15);

    s16x8 a[4];
    const unsigned short* ap = xa + (size_t)arow * 256 + (lane >> 4) * 8;
    #pragma unroll
    for (int kk = 0; kk < 4; ++kk) a[kk] = *(const s16x8*)(ap + kk * 32);

    f32x4 acc[24];
    #pragma unroll
    for (int nt = 0; nt < 24; ++nt) acc[nt] = (f32x4){0.f, 0.f, 0.f, 0.f};

    const s16x8* wfv = (const s16x8*)wf;
    #pragma unroll
    for (int nt = 0; nt < 24; ++nt) {
        #pragma unroll
        for (int kk = 0; kk < 4; ++kk) {
            s16x8 b = wfv[(nt * 4 + kk) * 64 + lane];
            acc[nt] = mfma_bf16(a[kk], b, acc[nt]);
        }
    }

    const int colb = lane & 15;
    const int rbase = row0 + (lane >> 4) * 4;
    #pragma unroll
    for (int nt = 0; nt < 24; ++nt) {
        const int mtx = nt >> 3;                  // 0:Q 1:K 2:V
        const int nc = (nt & 7) * 16 + colb;      // 0..127
        const float* bias_p = (mtx == 0) ? bq : ((mtx == 1) ? bk : bv);
        unsigned short* O = (mtx == 0) ? Qb : ((mtx == 1) ? Kb : Vb);
        float bias = bias_p[nc];
        #pragma unroll
        for (int r = 0; r < 4; ++r)
            O[(size_t)(rbase + r) * 128 + nc] = f2bf(acc[nt][r] + bias);
    }
}

// ---------------- fused per-node attention (bf16 Q/K/V, online softmax) ----------------
__global__ void attn_kernel(const unsigned short* __restrict__ Qb,
                            const unsigned short* __restrict__ Kb,
                            const unsigned short* __restrict__ Vb,
                            const int* __restrict__ row_start, const int* __restrict__ colS,
                            unsigned short* __restrict__ xa) {
    const int i = blockIdx.x;
    const int d = threadIdx.x;
    const float q = bf2f(Qb[(size_t)i * 128 + d]);
    const int e0 = row_start[i], e1 = row_start[i + 1];

    float m = -INFINITY, l = 0.f, acc = 0.f;
    for (int e = e0; e < e1; ++e) {
        int c = colS[e];
        float p = q * bf2f(Kb[(size_t)c * 128 + d]);
        p += __shfl_xor(p, 16, 32);
        p += __shfl_xor(p, 8, 32);
        p += __shfl_xor(p, 4, 32);
        p += __shfl_xor(p, 2, 32);
        p += __shfl_xor(p, 1, 32);
        float s = p * 0.17677669529663689f;
        float mn = fmaxf(m, s);
        float fac = __expf(m - mn);
        float ev = __expf(s - mn);
        l = l * fac + ev;
        acc = acc * fac + ev * bf2f(Vb[(size_t)c * 128 + d]);
        m = mn;
    }
    xa[(size_t)i * 256 + 128 + d] = f2bf((l > 0.f) ? acc / l : 0.f);
}

// ---------------- MLP1 via MFMA + ReLU + LayerNorm -> bf16 h ----------------
__global__ __launch_bounds__(256) void gemm_mlp1_kernel(
        const unsigned short* __restrict__ xa, const unsigned short* __restrict__ w1f,
        const float* __restrict__ b1, const float* __restrict__ ln_g,
        const float* __restrict__ ln_b, unsigned short* __restrict__ hb) {
    const int wave = threadIdx.x >> 6, lane = threadIdx.x & 63;
    const int row0 = blockIdx.x * 64 + wave * 16;
    const int arow = row0 + (lane & 15);

    s16x8 a[8];
    const unsigned short* ap = xa + (size_t)arow * 256 + (lane >> 4) * 8;
    #pragma unroll
    for (int kk = 0; kk < 8; ++kk) a[kk] = *(const s16x8*)(ap + kk * 32);

    f32x4 acc[8];
    #pragma unroll
    for (int nt = 0; nt < 8; ++nt) acc[nt] = (f32x4){0.f, 0.f, 0.f, 0.f};

    const s16x8* wfv = (const s16x8*)w1f;
    #pragma unroll
    for (int nt = 0; nt < 8; ++nt) {
        #pragma unroll
        for (int kk = 0; kk < 8; ++kk) {
            s16x8 b = wfv[(nt * 8 + kk) * 64 + lane];
            acc[nt] = mfma_bf16(a[kk], b, acc[nt]);
        }
    }

    const int colb = lane & 15;
    // bias + relu
    #pragma unroll
    for (int nt = 0; nt < 8; ++nt) {
        float bias = b1[nt * 16 + colb];
        #pragma unroll
        for (int r = 0; r < 4; ++r) {
            float v = acc[nt][r] + bias;
            acc[nt][r] = v > 0.f ? v : 0.f;
        }
    }
    // per-row mean/var: reduce over 8 local ntiles then across 16 lanes
    float mu[4], rs[4];
    #pragma unroll
    for (int r = 0; r < 4; ++r) {
        float s = 0.f, q = 0.f;
        #pragma unroll
        for (int nt = 0; nt < 8; ++nt) { float v = acc[nt][r]; s += v; q += v * v; }
        #pragma unroll
        for (int msk = 1; msk < 16; msk <<= 1) {
            s += __shfl_xor(s, msk, 16);
            q += __shfl_xor(q, msk, 16);
        }
        float m_ = s * (1.f / 128.f);
        float var = q * (1.f / 128.f) - m_ * m_;
        mu[r] = m_;
        rs[r] = rsqrtf(var + LN_EPS);
    }
    const int rbase = row0 + (lane >> 4) * 4;
    #pragma unroll
    for (int nt = 0; nt < 8; ++nt) {
        int col = nt * 16 + colb;
        float g = ln_g[col], bb = ln_b[col];
        #pragma unroll
        for (int r = 0; r < 4; ++r) {
            float h = (acc[nt][r] - mu[r]) * rs[r] * g + bb;
            hb[(size_t)(rbase + r) * 128 + col] = f2bf(h);
        }
    }
}

// ---------------- MLP2 via MFMA + bias + residual -> f32 out ----------------
__global__ __launch_bounds__(256) void gemm_mlp2_kernel(
        const unsigned short* __restrict__ hb, const unsigned short* __restrict__ w2f,
        const float* __restrict__ b2, const float* __restrict__ x,
        float* __restrict__ out) {
    const int wave = threadIdx.x >> 6, lane = threadIdx.x & 63;
    const int row0 = blockIdx.x * 64 + wave * 16;
    const int arow = row0 + (lane & 15);

    s16x8 a[4];
    const unsigned short* ap = hb + (size_t)arow * 128 + (lane >> 4) * 8;
    #pragma unroll
    for (int kk = 0; kk < 4; ++kk) a[kk] = *(const s16x8*)(ap + kk * 32);

    f32x4 acc[8];
    #pragma unroll
    for (int nt = 0; nt < 8; ++nt) acc[nt] = (f32x4){0.f, 0.f, 0.f, 0.f};

    const s16x8* wfv = (const s16x8*)w2f;
    #pragma unroll
    for (int nt = 0; nt < 8; ++nt) {
        #pragma unroll
        for (int kk = 0; kk < 4; ++kk) {
            s16x8 b = wfv[(nt * 4 + kk) * 64 + lane];
            acc[nt] = mfma_bf16(a[kk], b, acc[nt]);
        }
    }

    const int colb = lane & 15;
    const int rbase = row0 + (lane >> 4) * 4;
    #pragma unroll
    for (int nt = 0; nt < 8; ++nt) {
        int col = nt * 16 + colb;
        float bias = b2[col];
        #pragma unroll
        for (int r = 0; r < 4; ++r) {
            int row = rbase + r;
            if (row < NN)
                out[(size_t)row * 128 + col] = acc[nt][r] + bias + x[(size_t)row * 128 + col];
        }
    }
}

extern "C" void kernel_launch(void* const* d_in, const int* in_sizes, int n_in,
                              void* d_out, int out_size, void* d_ws, size_t ws_size,
                              hipStream_t stream) {
    const float* x    = (const float*)d_in[0];
    const void*  ei   = d_in[1];
    const float* Wq   = (const float*)d_in[2];
    const float* bq   = (const float*)d_in[3];
    const float* Wk   = (const float*)d_in[4];
    const float* bk   = (const float*)d_in[5];
    const float* Wv   = (const float*)d_in[6];
    const float* bv   = (const float*)d_in[7];
    const float* W1   = (const float*)d_in[8];
    const float* b1   = (const float*)d_in[9];
    const float* ln_g = (const float*)d_in[10];
    const float* ln_b = (const float*)d_in[11];
    const float* W2   = (const float*)d_in[12];
    const float* b2   = (const float*)d_in[13];
    float* out = (float*)d_out;

    char* ws = (char*)d_ws;
    size_t off = 0;
    auto alloc = [&](size_t bytes) {
        size_t o = off;
        off = (off + bytes + 255) & ~(size_t)255;
        return o;
    };
    size_t flag_o = alloc(sizeof(int));
    size_t rowi_o = alloc((size_t)EE * sizeof(int));
    size_t coli_o = alloc((size_t)EE * sizeof(int));
    size_t deg_o  = alloc((size_t)NN * sizeof(int));
    size_t cur_o  = alloc((size_t)NN * sizeof(int));
    size_t rs_o   = alloc((size_t)(NN + 1) * sizeof(int));
    size_t colS_o = alloc((size_t)EE * sizeof(int));
    size_t xa_o   = alloc((size_t)ROWS_PAD * 256 * sizeof(unsigned short));
    size_t wf_o   = alloc((size_t)98304 * sizeof(unsigned short));
    size_t Qb_o   = alloc((size_t)ROWS_PAD * 128 * sizeof(unsigned short));
    size_t Kb_o   = alloc((size_t)ROWS_PAD * 128 * sizeof(unsigned short));
    size_t Vb_o   = alloc((size_t)ROWS_PAD * 128 * sizeof(unsigned short));
    size_t hb_o   = Qb_o;  // h reuses Q (dead after attn)

    int* flag   = (int*)(ws + flag_o);
    int* rowi   = (int*)(ws + rowi_o);
    int* coli   = (int*)(ws + coli_o);
    int* deg    = (int*)(ws + deg_o);
    int* cursor = (int*)(ws + cur_o);
    int* rstart = (int*)(ws + rs_o);
    int* colS   = (int*)(ws + colS_o);
    unsigned short* xa = (unsigned short*)(ws + xa_o);
    unsigned short* wf = (unsigned short*)(ws + wf_o);
    unsigned short* Qb = (unsigned short*)(ws + Qb_o);
    unsigned short* Kb = (unsigned short*)(ws + Kb_o);
    unsigned short* Vb = (unsigned short*)(ws + Vb_o);
    unsigned short* hb = (unsigned short*)(ws + hb_o);

    hipMemsetAsync(ws + deg_o, 0, (size_t)NN * sizeof(int), stream);

    detect_idx_kernel<<<1, 64, 0, stream>>>((const unsigned int*)ei, flag);
    convert_hist_kernel<<<(EE + 255) / 256, 256, 0, stream>>>(ei, flag, rowi, coli, deg);
    scan_kernel<<<1, 1024, 0, stream>>>(deg, rstart, cursor);
    scatter_kernel<<<(EE + 255) / 256, 256, 0, stream>>>(rowi, coli, cursor, colS);

    pack_x_kernel<<<(NN * HH / 4 + 255) / 256, 256, 0, stream>>>(x, xa);
    pack_w_kernel<<<98304 / 256, 256, 0, stream>>>(Wq, Wk, Wv, W1, W2, wf);

    gemm_qkv_kernel<<<ROWS_PAD / 64, 256, 0, stream>>>(xa, wf, bq, bk, bv, Qb, Kb, Vb);

    attn_kernel<<<NN, 128, 0, stream>>>(Qb, Kb, Vb, rstart, colS, xa);

    gemm_mlp1_kernel<<<ROWS_PAD / 64, 256, 0, stream>>>(xa, wf + 49152, b1, ln_g, ln_b, hb);

    gemm_mlp2_kernel<<<ROWS_PAD / 64, 256, 0, stream>>>(hb, wf + 81920, b2, x, out);
}

// Round 4
// 376.025 us; speedup vs baseline: 2.5251x; 1.0777x over previous
//
#include <hip/hip_runtime.h>
#include <hip/hip_bf16.h>

#define NN 50000
#define HH 128
#define NHEAD 4
#define HD 32
#define EE 800000
#define LN_EPS 1e-5f
#define ROWS_PAD 50048   // 782 * 64

typedef __bf16 bf16x8 __attribute__((ext_vector_type(8)));
typedef short  s16x8  __attribute__((ext_vector_type(8)));
typedef float  f32x4  __attribute__((ext_vector_type(4)));

__device__ __forceinline__ f32x4 mfma_bf16(s16x8 a, s16x8 b, f32x4 c) {
    return __builtin_amdgcn_mfma_f32_16x16x32_bf16((bf16x8)a, (bf16x8)b, c, 0, 0, 0);
}

__device__ __forceinline__ unsigned short f2bf(float f) {
    union { float f; unsigned int u; } v; v.f = f;
    unsigned int u = v.u + 0x7FFFu + ((v.u >> 16) & 1u);  // RNE
    return (unsigned short)(u >> 16);
}

// ---------------- index dtype probe ----------------
__global__ void detect_idx_kernel(const unsigned int* __restrict__ buf, int* __restrict__ flag) {
    if (blockIdx.x == 0 && threadIdx.x == 0) {
        int is64 = 1;
        for (int i = 0; i < 64; ++i) {
            if (buf[2 * i + 1] != 0u) { is64 = 0; break; }
        }
        *flag = is64;
    }
}

__global__ void convert_hist_kernel(const void* __restrict__ ei, const int* __restrict__ flag,
                                    int* __restrict__ rowi, int* __restrict__ coli,
                                    int* __restrict__ deg) {
    int i = blockIdx.x * blockDim.x + threadIdx.x;
    if (i >= EE) return;
    int r, c;
    if (*flag) {
        const long long* p = (const long long*)ei;
        r = (int)p[i];
        c = (int)p[EE + i];
    } else {
        const int* p = (const int*)ei;
        r = p[i];
        c = p[EE + i];
    }
    rowi[i] = r;
    coli[i] = c;
    atomicAdd(&deg[r], 1);
}

__global__ __launch_bounds__(1024) void scan_kernel(const int* __restrict__ deg,
                                                    int* __restrict__ row_start,
                                                    int* __restrict__ cursor) {
    __shared__ int buf[2][1024];
    const int t = threadIdx.x;
    const int CH = (NN + 1023) / 1024;  // 49
    const int lo = t * CH;
    const int hi = (lo + CH < NN) ? lo + CH : NN;
    int sum = 0;
    for (int i = lo; i < hi; ++i) sum += deg[i];
    buf[0][t] = sum;
    __syncthreads();
    int src = 0;
    for (int ofs = 1; ofs < 1024; ofs <<= 1) {
        int v = buf[src][t];
        if (t >= ofs) v += buf[src][t - ofs];
        buf[src ^ 1][t] = v;
        __syncthreads();
        src ^= 1;
    }
    int excl = (t == 0) ? 0 : buf[src][t - 1];
    int run = excl;
    for (int i = lo; i < hi; ++i) {
        row_start[i] = run;
        cursor[i] = run;
        run += deg[i];
    }
    if (hi == NN) row_start[NN] = run;
}

__global__ void scatter_kernel(const int* __restrict__ rowi, const int* __restrict__ coli,
                               int* __restrict__ cursor, int* __restrict__ colS) {
    int i = blockIdx.x * blockDim.x + threadIdx.x;
    if (i >= EE) return;
    int pos = atomicAdd(&cursor[rowi[i]], 1);
    colS[pos] = coli[i];
}

// ---------------- fused pack: x -> bf16 xa left half; weights -> MFMA fragments ----------------
// fragment element index: (((ntile*KSTEPS + kk)*64 + lane)*8 + j)
// value = W[kk*32 + (lane>>4)*8 + j][ntile*16 + (lane&15)]
#define PACKX_T 1600000   // NN*HH/4
__global__ void pack_kernel(const float* __restrict__ x,
                            const float* __restrict__ Wq, const float* __restrict__ Wk,
                            const float* __restrict__ Wv, const float* __restrict__ W1,
                            const float* __restrict__ W2,
                            unsigned short* __restrict__ xa, unsigned short* __restrict__ wf) {
    int t = blockIdx.x * blockDim.x + threadIdx.x;
    if (t < PACKX_T) {
        int r = t >> 5;
        int c4 = (t & 31) << 2;
        float4 v = *(const float4*)(x + (size_t)r * HH + c4);
        ushort4 o;
        o.x = f2bf(v.x); o.y = f2bf(v.y); o.z = f2bf(v.z); o.w = f2bf(v.w);
        *(ushort4*)(xa + (size_t)r * 256 + c4) = o;
        return;
    }
    int i = t - PACKX_T;
    if (i >= 98304) return;
    float val;
    if (i < 49152) {                      // QKV: ntiles=24, ksteps=4, K=128
        int j = i & 7, lane = (i >> 3) & 63, kk = (i >> 9) & 3, nt = i >> 11;
        int k = kk * 32 + (lane >> 4) * 8 + j;
        int n = nt * 16 + (lane & 15);    // 0..383
        const float* W = (n < 128) ? Wq : ((n < 256) ? Wk : Wv);
        val = W[k * HH + (n & 127)];
    } else if (i < 81920) {               // W1: ntiles=8, ksteps=8, K=256
        int local = i - 49152;
        int j = local & 7, lane = (local >> 3) & 63, kk = (local >> 9) & 7, nt = local >> 12;
        int k = kk * 32 + (lane >> 4) * 8 + j;
        int n = nt * 16 + (lane & 15);
        val = W1[k * HH + n];
    } else {                              // W2: ntiles=8, ksteps=4, K=128
        int local = i - 81920;
        int j = local & 7, lane = (local >> 3) & 63, kk = (local >> 9) & 3, nt = local >> 11;
        int k = kk * 32 + (lane >> 4) * 8 + j;
        int n = nt * 16 + (lane & 15);
        val = W2[k * HH + n];
    }
    wf[i] = f2bf(val);
}

// ---------------- QKV GEMM via MFMA ----------------
__global__ __launch_bounds__(256) void gemm_qkv_kernel(
        const unsigned short* __restrict__ xa, const unsigned short* __restrict__ wf,
        const float* __restrict__ bq, const float* __restrict__ bk, const float* __restrict__ bv,
        unsigned short* __restrict__ Qb, unsigned short* __restrict__ Kb,
        unsigned short* __restrict__ Vb) {
    const int wave = threadIdx.x >> 6, lane = threadIdx.x & 63;
    const int row0 = blockIdx.x * 64 + wave * 16;
    const int arow = row0 + (lane & 15);

    s16x8 a[4];
    const unsigned short* ap = xa + (size_t)arow * 256 + (lane >> 4) * 8;
    #pragma unroll
    for (int kk = 0; kk < 4; ++kk) a[kk] = *(const s16x8*)(ap + kk * 32);

    f32x4 acc[24];
    #pragma unroll
    for (int nt = 0; nt < 24; ++nt) acc[nt] = (f32x4){0.f, 0.f, 0.f, 0.f};

    const s16x8* wfv = (const s16x8*)wf;
    #pragma unroll
    for (int nt = 0; nt < 24; ++nt) {
        #pragma unroll
        for (int kk = 0; kk < 4; ++kk) {
            s16x8 b = wfv[(nt * 4 + kk) * 64 + lane];
            acc[nt] = mfma_bf16(a[kk], b, acc[nt]);
        }
    }

    const int colb = lane & 15;
    const int rbase = row0 + (lane >> 4) * 4;
    #pragma unroll
    for (int nt = 0; nt < 24; ++nt) {
        const int mtx = nt >> 3;                  // 0:Q 1:K 2:V
        const int nc = (nt & 7) * 16 + colb;      // 0..127
        const float* bias_p = (mtx == 0) ? bq : ((mtx == 1) ? bk : bv);
        unsigned short* O = (mtx == 0) ? Qb : ((mtx == 1) ? Kb : Vb);
        float bias = bias_p[nc];
        #pragma unroll
        for (int r = 0; r < 4; ++r)
            O[(size_t)(rbase + r) * 128 + nc] = f2bf(acc[nt][r] + bias);
    }
}

// ---------------- fused per-node attention: one wave per node ----------------
// score phase: lane = local_edge*4 + head  (lane-local 32-dim dot, no shuffles)
// PV phase:    lane = dim pair (2*lane, 2*lane+1), head g = lane>>4
__global__ __launch_bounds__(256) void attn_kernel(
        const unsigned short* __restrict__ Qb, const unsigned short* __restrict__ Kb,
        const unsigned short* __restrict__ Vb, const int* __restrict__ rstart,
        const int* __restrict__ colS, unsigned short* __restrict__ xa) {
    const int wave = threadIdx.x >> 6;
    const int lane = threadIdx.x & 63;
    const int i = blockIdx.x * 4 + wave;
    if (i >= NN) return;
    const int h = lane & 3;       // head (score phase)
    const int le = lane >> 2;     // local edge 0..15 (score phase)
    const int g = lane >> 4;      // head (PV phase)
    const int e0 = rstart[i], e1 = rstart[i + 1];
    const int deg = e1 - e0;

    // unpack this head's Q slice into 32 f32 regs
    float qf[32];
    {
        const uint4* qp = (const uint4*)(Qb + (size_t)i * 128 + h * 32);
        #pragma unroll
        for (int cch = 0; cch < 4; ++cch) {
            uint4 qv = qp[cch];
            unsigned int w_[4] = {qv.x, qv.y, qv.z, qv.w};
            #pragma unroll
            for (int dd = 0; dd < 4; ++dd) {
                qf[cch * 8 + dd * 2]     = __uint_as_float(w_[dd] << 16);
                qf[cch * 8 + dd * 2 + 1] = __uint_as_float(w_[dd] & 0xffff0000u);
            }
        }
    }

    float m = -INFINITY, l = 0.f;
    float accx = 0.f, accy = 0.f;

    for (int c0 = 0; c0 < deg; c0 += 16) {
        const int cnt = min(16, deg - c0);
        int col = 0;
        float s = -INFINITY;
        if (le < cnt) {
            col = colS[e0 + c0 + le];
            const uint4* kp = (const uint4*)(Kb + (size_t)col * 128 + h * 32);
            float dot = 0.f;
            #pragma unroll
            for (int cch = 0; cch < 4; ++cch) {
                uint4 kv = kp[cch];
                unsigned int w_[4] = {kv.x, kv.y, kv.z, kv.w};
                #pragma unroll
                for (int dd = 0; dd < 4; ++dd) {
                    dot += qf[cch * 8 + dd * 2]     * __uint_as_float(w_[dd] << 16);
                    dot += qf[cch * 8 + dd * 2 + 1] * __uint_as_float(w_[dd] & 0xffff0000u);
                }
            }
            s = dot * 0.17677669529663689f;   // 1/sqrt(32)
        }
        // per-head max over the 16 edge-lanes (lane stride 4)
        float sm = s;
        sm = fmaxf(sm, __shfl_xor(sm, 4));
        sm = fmaxf(sm, __shfl_xor(sm, 8));
        sm = fmaxf(sm, __shfl_xor(sm, 16));
        sm = fmaxf(sm, __shfl_xor(sm, 32));
        const float mn = fmaxf(m, sm);
        const float p = (le < cnt) ? __expf(s - mn) : 0.f;
        float ps = p;
        ps += __shfl_xor(ps, 4);
        ps += __shfl_xor(ps, 8);
        ps += __shfl_xor(ps, 16);
        ps += __shfl_xor(ps, 32);
        const float fac = __expf(m - mn);   // first chunk: exp(-inf)=0
        l = l * fac + ps;
        m = mn;
        // PV: rescale then accumulate this chunk
        const float facbc = __shfl(fac, g);   // head g's fac lives in lane g (le=0)
        accx *= facbc;
        accy *= facbc;
        #pragma unroll 2
        for (int e = 0; e < cnt; ++e) {
            const int   cbc = __shfl(col, 4 * e);
            const float pbc = __shfl(p, 4 * e + g);
            const unsigned int v2 =
                *(const unsigned int*)(Vb + (size_t)cbc * 128 + 2 * lane);
            accx += pbc * __uint_as_float(v2 << 16);
            accy += pbc * __uint_as_float(v2 & 0xffff0000u);
        }
    }

    const float lf = __shfl(l, g);
    const float rinv = (lf > 0.f) ? 1.f / lf : 0.f;
    const unsigned int outw =
        ((unsigned int)f2bf(accy * rinv) << 16) | (unsigned int)f2bf(accx * rinv);
    *(unsigned int*)(xa + (size_t)i * 256 + 128 + 2 * lane) = outw;
}

// ---------------- MLP1 via MFMA + ReLU + LayerNorm -> bf16 h ----------------
__global__ __launch_bounds__(256) void gemm_mlp1_kernel(
        const unsigned short* __restrict__ xa, const unsigned short* __restrict__ w1f,
        const float* __restrict__ b1, const float* __restrict__ ln_g,
        const float* __restrict__ ln_b, unsigned short* __restrict__ hb) {
    const int wave = threadIdx.x >> 6, lane = threadIdx.x & 63;
    const int row0 = blockIdx.x * 64 + wave * 16;
    const int arow = row0 + (lane & 15);

    s16x8 a[8];
    const unsigned short* ap = xa + (size_t)arow * 256 + (lane >> 4) * 8;
    #pragma unroll
    for (int kk = 0; kk < 8; ++kk) a[kk] = *(const s16x8*)(ap + kk * 32);

    f32x4 acc[8];
    #pragma unroll
    for (int nt = 0; nt < 8; ++nt) acc[nt] = (f32x4){0.f, 0.f, 0.f, 0.f};

    const s16x8* wfv = (const s16x8*)w1f;
    #pragma unroll
    for (int nt = 0; nt < 8; ++nt) {
        #pragma unroll
        for (int kk = 0; kk < 8; ++kk) {
            s16x8 b = wfv[(nt * 8 + kk) * 64 + lane];
            acc[nt] = mfma_bf16(a[kk], b, acc[nt]);
        }
    }

    const int colb = lane & 15;
    #pragma unroll
    for (int nt = 0; nt < 8; ++nt) {
        float bias = b1[nt * 16 + colb];
        #pragma unroll
        for (int r = 0; r < 4; ++r) {
            float v = acc[nt][r] + bias;
            acc[nt][r] = v > 0.f ? v : 0.f;
        }
    }
    float mu[4], rs[4];
    #pragma unroll
    for (int r = 0; r < 4; ++r) {
        float s = 0.f, q = 0.f;
        #pragma unroll
        for (int nt = 0; nt < 8; ++nt) { float v = acc[nt][r]; s += v; q += v * v; }
        #pragma unroll
        for (int msk = 1; msk < 16; msk <<= 1) {
            s += __shfl_xor(s, msk, 16);
            q += __shfl_xor(q, msk, 16);
        }
        float m_ = s * (1.f / 128.f);
        float var = q * (1.f / 128.f) - m_ * m_;
        mu[r] = m_;
        rs[r] = rsqrtf(var + LN_EPS);
    }
    const int rbase = row0 + (lane >> 4) * 4;
    #pragma unroll
    for (int nt = 0; nt < 8; ++nt) {
        int col = nt * 16 + colb;
        float g = ln_g[col], bb = ln_b[col];
        #pragma unroll
        for (int r = 0; r < 4; ++r) {
            float h = (acc[nt][r] - mu[r]) * rs[r] * g + bb;
            hb[(size_t)(rbase + r) * 128 + col] = f2bf(h);
        }
    }
}

// ---------------- MLP2 via MFMA + bias + residual -> f32 out ----------------
__global__ __launch_bounds__(256) void gemm_mlp2_kernel(
        const unsigned short* __restrict__ hb, const unsigned short* __restrict__ w2f,
        const float* __restrict__ b2, const float* __restrict__ x,
        float* __restrict__ out) {
    const int wave = threadIdx.x >> 6, lane = threadIdx.x & 63;
    const int row0 = blockIdx.x * 64 + wave * 16;
    const int arow = row0 + (lane & 15);

    s16x8 a[4];
    const unsigned short* ap = hb + (size_t)arow * 128 + (lane >> 4) * 8;
    #pragma unroll
    for (int kk = 0; kk < 4; ++kk) a[kk] = *(const s16x8*)(ap + kk * 32);

    f32x4 acc[8];
    #pragma unroll
    for (int nt = 0; nt < 8; ++nt) acc[nt] = (f32x4){0.f, 0.f, 0.f, 0.f};

    const s16x8* wfv = (const s16x8*)w2f;
    #pragma unroll
    for (int nt = 0; nt < 8; ++nt) {
        #pragma unroll
        for (int kk = 0; kk < 4; ++kk) {
            s16x8 b = wfv[(nt * 4 + kk) * 64 + lane];
            acc[nt] = mfma_bf16(a[kk], b, acc[nt]);
        }
    }

    const int colb = lane & 15;
    const int rbase = row0 + (lane >> 4) * 4;
    #pragma unroll
    for (int nt = 0; nt < 8; ++nt) {
        int col = nt * 16 + colb;
        float bias = b2[col];
        #pragma unroll
        for (int r = 0; r < 4; ++r) {
            int row = rbase + r;
            if (row < NN)
                out[(size_t)row * 128 + col] = acc[nt][r] + bias + x[(size_t)row * 128 + col];
        }
    }
}

extern "C" void kernel_launch(void* const* d_in, const int* in_sizes, int n_in,
                              void* d_out, int out_size, void* d_ws, size_t ws_size,
                              hipStream_t stream) {
    const float* x    = (const float*)d_in[0];
    const void*  ei   = d_in[1];
    const float* Wq   = (const float*)d_in[2];
    const float* bq   = (const float*)d_in[3];
    const float* Wk   = (const float*)d_in[4];
    const float* bk   = (const float*)d_in[5];
    const float* Wv   = (const float*)d_in[6];
    const float* bv   = (const float*)d_in[7];
    const float* W1   = (const float*)d_in[8];
    const float* b1   = (const float*)d_in[9];
    const float* ln_g = (const float*)d_in[10];
    const float* ln_b = (const float*)d_in[11];
    const float* W2   = (const float*)d_in[12];
    const float* b2   = (const float*)d_in[13];
    float* out = (float*)d_out;

    char* ws = (char*)d_ws;
    size_t off = 0;
    auto alloc = [&](size_t bytes) {
        size_t o = off;
        off = (off + bytes + 255) & ~(size_t)255;
        return o;
    };
    size_t flag_o = alloc(sizeof(int));
    size_t rowi_o = alloc((size_t)EE * sizeof(int));
    size_t coli_o = alloc((size_t)EE * sizeof(int));
    size_t deg_o  = alloc((size_t)NN * sizeof(int));
    size_t cur_o  = alloc((size_t)NN * sizeof(int));
    size_t rs_o   = alloc((size_t)(NN + 1) * sizeof(int));
    size_t colS_o = alloc((size_t)EE * sizeof(int));
    size_t xa_o   = alloc((size_t)ROWS_PAD * 256 * sizeof(unsigned short));
    size_t wf_o   = alloc((size_t)98304 * sizeof(unsigned short));
    size_t Qb_o   = alloc((size_t)ROWS_PAD * 128 * sizeof(unsigned short));
    size_t Kb_o   = alloc((size_t)ROWS_PAD * 128 * sizeof(unsigned short));
    size_t Vb_o   = alloc((size_t)ROWS_PAD * 128 * sizeof(unsigned short));
    size_t hb_o   = Qb_o;  // h reuses Q (dead after attn)

    int* flag   = (int*)(ws + flag_o);
    int* rowi   = (int*)(ws + rowi_o);
    int* coli   = (int*)(ws + coli_o);
    int* deg    = (int*)(ws + deg_o);
    int* cursor = (int*)(ws + cur_o);
    int* rstart = (int*)(ws + rs_o);
    int* colS   = (int*)(ws + colS_o);
    unsigned short* xa = (unsigned short*)(ws + xa_o);
    unsigned short* wf = (unsigned short*)(ws + wf_o);
    unsigned short* Qb = (unsigned short*)(ws + Qb_o);
    unsigned short* Kb = (unsigned short*)(ws + Kb_o);
    unsigned short* Vb = (unsigned short*)(ws + Vb_o);
    unsigned short* hb = (unsigned short*)(ws + hb_o);

    hipMemsetAsync(ws + deg_o, 0, (size_t)NN * sizeof(int), stream);

    detect_idx_kernel<<<1, 64, 0, stream>>>((const unsigned int*)ei, flag);
    convert_hist_kernel<<<(EE + 255) / 256, 256, 0, stream>>>(ei, flag, rowi, coli, deg);
    scan_kernel<<<1, 1024, 0, stream>>>(deg, rstart, cursor);
    scatter_kernel<<<(EE + 255) / 256, 256, 0, stream>>>(rowi, coli, cursor, colS);

    pack_kernel<<<(PACKX_T + 98304 + 255) / 256, 256, 0, stream>>>(
        x, Wq, Wk, Wv, W1, W2, xa, wf);

    gemm_qkv_kernel<<<ROWS_PAD / 64, 256, 0, stream>>>(xa, wf, bq, bk, bv, Qb, Kb, Vb);

    attn_kernel<<<(NN + 3) / 4, 256, 0, stream>>>(Qb, Kb, Vb, rstart, colS, xa);

    gemm_mlp1_kernel<<<ROWS_PAD / 64, 256, 0, stream>>>(xa, wf + 49152, b1, ln_g, ln_b, hb);

    gemm_mlp2_kernel<<<ROWS_PAD / 64, 256, 0, stream>>>(hb, wf + 81920, b2, x, out);
}

// Round 5
// 233.253 us; speedup vs baseline: 4.0707x; 1.6121x over previous
//
#include <hip/hip_runtime.h>
#include <hip/hip_bf16.h>

#define NN 50000
#define HH 128
#define NHEAD 4
#define HD 32
#define EE 800000
#define LN_EPS 1e-5f
#define ROWS_PAD 50048   // 782 * 64
#define SCAN_NB 98       // ceil(NN/512)

typedef __bf16 bf16x8 __attribute__((ext_vector_type(8)));
typedef short  s16x8  __attribute__((ext_vector_type(8)));
typedef float  f32x4  __attribute__((ext_vector_type(4)));

__device__ __forceinline__ f32x4 mfma_bf16(s16x8 a, s16x8 b, f32x4 c) {
    return __builtin_amdgcn_mfma_f32_16x16x32_bf16((bf16x8)a, (bf16x8)b, c, 0, 0, 0);
}

__device__ __forceinline__ unsigned short f2bf(float f) {
    union { float f; unsigned int u; } v; v.f = f;
    unsigned int u = v.u + 0x7FFFu + ((v.u >> 16) & 1u);  // RNE
    return (unsigned short)(u >> 16);
}

// ---------------- index dtype probe ----------------
__global__ void detect_idx_kernel(const unsigned int* __restrict__ buf, int* __restrict__ flag) {
    if (blockIdx.x == 0 && threadIdx.x == 0) {
        int is64 = 1;
        for (int i = 0; i < 64; ++i) {
            if (buf[2 * i + 1] != 0u) { is64 = 0; break; }
        }
        *flag = is64;
    }
}

__global__ void convert_hist_kernel(const void* __restrict__ ei, const int* __restrict__ flag,
                                    int* __restrict__ rowi, int* __restrict__ coli,
                                    int* __restrict__ deg) {
    int i = blockIdx.x * blockDim.x + threadIdx.x;
    if (i >= EE) return;
    int r, c;
    if (*flag) {
        const long long* p = (const long long*)ei;
        r = (int)p[i];
        c = (int)p[EE + i];
    } else {
        const int* p = (const int*)ei;
        r = p[i];
        c = p[EE + i];
    }
    rowi[i] = r;
    coli[i] = c;
    atomicAdd(&deg[r], 1);
}

// ---------------- multi-block exclusive scan of degrees ----------------
// A: per-block (512 elems) reduce -> bsum
__global__ __launch_bounds__(512) void scan_a_kernel(const int* __restrict__ deg,
                                                     int* __restrict__ bsum) {
    __shared__ int red[8];
    const int t = threadIdx.x;
    const int gid = blockIdx.x * 512 + t;
    int v = (gid < NN) ? deg[gid] : 0;
    #pragma unroll
    for (int o = 1; o < 64; o <<= 1) v += __shfl_xor(v, o);
    if ((t & 63) == 0) red[t >> 6] = v;
    __syncthreads();
    if (t == 0) {
        int s = 0;
        #pragma unroll
        for (int k = 0; k < 8; ++k) s += red[k];
        bsum[blockIdx.x] = s;
    }
}

// B: single-wave exclusive scan of the 98 block sums
__global__ void scan_b_kernel(const int* __restrict__ bsum, int* __restrict__ boff) {
    const int lane = threadIdx.x;  // 64 threads
    const int i0 = lane * 2, i1 = lane * 2 + 1;
    int a = (i0 < SCAN_NB) ? bsum[i0] : 0;
    int b = (i1 < SCAN_NB) ? bsum[i1] : 0;
    int incl = a + b;
    const int own = incl;
    #pragma unroll
    for (int o = 1; o < 64; o <<= 1) {
        int u = __shfl_up(incl, o);
        if (lane >= o) incl += u;
    }
    int excl = incl - own;
    if (i0 < SCAN_NB) boff[i0] = excl;
    if (i1 < SCAN_NB) boff[i1] = excl + a;
}

// C: block-local exclusive scan + block offset -> row_start, cursor
__global__ __launch_bounds__(512) void scan_c_kernel(const int* __restrict__ deg,
                                                     const int* __restrict__ boff,
                                                     int* __restrict__ rstart,
                                                     int* __restrict__ cursor) {
    __shared__ int wsum[8];
    const int t = threadIdx.x;
    const int gid = blockIdx.x * 512 + t;
    const int lane = t & 63, w = t >> 6;
    int v = (gid < NN) ? deg[gid] : 0;
    int incl = v;
    #pragma unroll
    for (int o = 1; o < 64; o <<= 1) {
        int u = __shfl_up(incl, o);
        if (lane >= o) incl += u;
    }
    if (lane == 63) wsum[w] = incl;
    __syncthreads();
    int woff = 0;
    for (int k = 0; k < w; ++k) woff += wsum[k];
    int excl = boff[blockIdx.x] + woff + incl - v;
    if (gid < NN) { rstart[gid] = excl; cursor[gid] = excl; }
    if (gid == 0) rstart[NN] = EE;  // total degree == edge count
}

__global__ void scatter_kernel(const int* __restrict__ rowi, const int* __restrict__ coli,
                               int* __restrict__ cursor, int* __restrict__ colS) {
    int i = blockIdx.x * blockDim.x + threadIdx.x;
    if (i >= EE) return;
    int pos = atomicAdd(&cursor[rowi[i]], 1);
    colS[pos] = coli[i];
}

// ---------------- fused pack: x -> bf16 xa left half; weights -> MFMA fragments ----------------
// fragment element index: (((ntile*KSTEPS + kk)*64 + lane)*8 + j)
// value = W[kk*32 + (lane>>4)*8 + j][ntile*16 + (lane&15)]
#define PACKX_T 1600000   // NN*HH/4
__global__ void pack_kernel(const float* __restrict__ x,
                            const float* __restrict__ Wq, const float* __restrict__ Wk,
                            const float* __restrict__ Wv, const float* __restrict__ W1,
                            const float* __restrict__ W2,
                            unsigned short* __restrict__ xa, unsigned short* __restrict__ wf) {
    int t = blockIdx.x * blockDim.x + threadIdx.x;
    if (t < PACKX_T) {
        int r = t >> 5;
        int c4 = (t & 31) << 2;
        float4 v = *(const float4*)(x + (size_t)r * HH + c4);
        ushort4 o;
        o.x = f2bf(v.x); o.y = f2bf(v.y); o.z = f2bf(v.z); o.w = f2bf(v.w);
        *(ushort4*)(xa + (size_t)r * 256 + c4) = o;
        return;
    }
    int i = t - PACKX_T;
    if (i >= 98304) return;
    float val;
    if (i < 49152) {                      // QKV: ntiles=24, ksteps=4, K=128
        int j = i & 7, lane = (i >> 3) & 63, kk = (i >> 9) & 3, nt = i >> 11;
        int k = kk * 32 + (lane >> 4) * 8 + j;
        int n = nt * 16 + (lane & 15);    // 0..383
        const float* W = (n < 128) ? Wq : ((n < 256) ? Wk : Wv);
        val = W[k * HH + (n & 127)];
    } else if (i < 81920) {               // W1: ntiles=8, ksteps=8, K=256
        int local = i - 49152;
        int j = local & 7, lane = (local >> 3) & 63, kk = (local >> 9) & 7, nt = local >> 12;
        int k = kk * 32 + (lane >> 4) * 8 + j;
        int n = nt * 16 + (lane & 15);
        val = W1[k * HH + n];
    } else {                              // W2: ntiles=8, ksteps=4, K=128
        int local = i - 81920;
        int j = local & 7, lane = (local >> 3) & 63, kk = (local >> 9) & 3, nt = local >> 11;
        int k = kk * 32 + (lane >> 4) * 8 + j;
        int n = nt * 16 + (lane & 15);
        val = W2[k * HH + n];
    }
    wf[i] = f2bf(val);
}

// ---------------- QKV GEMM via MFMA ----------------
__global__ __launch_bounds__(256) void gemm_qkv_kernel(
        const unsigned short* __restrict__ xa, const unsigned short* __restrict__ wf,
        const float* __restrict__ bq, const float* __restrict__ bk, const float* __restrict__ bv,
        unsigned short* __restrict__ Qb, unsigned short* __restrict__ Kb,
        unsigned short* __restrict__ Vb) {
    const int wave = threadIdx.x >> 6, lane = threadIdx.x & 63;
    const int row0 = blockIdx.x * 64 + wave * 16;
    const int arow = row0 + (lane & 15);

    s16x8 a[4];
    const unsigned short* ap = xa + (size_t)arow * 256 + (lane >> 4) * 8;
    #pragma unroll
    for (int kk = 0; kk < 4; ++kk) a[kk] = *(const s16x8*)(ap + kk * 32);

    f32x4 acc[24];
    #pragma unroll
    for (int nt = 0; nt < 24; ++nt) acc[nt] = (f32x4){0.f, 0.f, 0.f, 0.f};

    const s16x8* wfv = (const s16x8*)wf;
    #pragma unroll
    for (int nt = 0; nt < 24; ++nt) {
        #pragma unroll
        for (int kk = 0; kk < 4; ++kk) {
            s16x8 b = wfv[(nt * 4 + kk) * 64 + lane];
            acc[nt] = mfma_bf16(a[kk], b, acc[nt]);
        }
    }

    const int colb = lane & 15;
    const int rbase = row0 + (lane >> 4) * 4;
    #pragma unroll
    for (int nt = 0; nt < 24; ++nt) {
        const int mtx = nt >> 3;                  // 0:Q 1:K 2:V
        const int nc = (nt & 7) * 16 + colb;      // 0..127
        const float* bias_p = (mtx == 0) ? bq : ((mtx == 1) ? bk : bv);
        unsigned short* O = (mtx == 0) ? Qb : ((mtx == 1) ? Kb : Vb);
        float bias = bias_p[nc];
        #pragma unroll
        for (int r = 0; r < 4; ++r)
            O[(size_t)(rbase + r) * 128 + nc] = f2bf(acc[nt][r] + bias);
    }
}

// ---------------- fused per-node attention: one wave per node ----------------
// score phase: lane = local_edge*4 + head  (lane-local 32-dim dot, no shuffles)
// PV phase:    lane = dim pair (2*lane, 2*lane+1), head g = lane>>4
__global__ __launch_bounds__(256) void attn_kernel(
        const unsigned short* __restrict__ Qb, const unsigned short* __restrict__ Kb,
        const unsigned short* __restrict__ Vb, const int* __restrict__ rstart,
        const int* __restrict__ colS, unsigned short* __restrict__ xa) {
    const int wave = threadIdx.x >> 6;
    const int lane = threadIdx.x & 63;
    const int i = blockIdx.x * 4 + wave;
    if (i >= NN) return;
    const int h = lane & 3;       // head (score phase)
    const int le = lane >> 2;     // local edge 0..15 (score phase)
    const int g = lane >> 4;      // head (PV phase)
    const int e0 = rstart[i], e1 = rstart[i + 1];
    const int deg = e1 - e0;

    // unpack this head's Q slice into 32 f32 regs
    float qf[32];
    {
        const uint4* qp = (const uint4*)(Qb + (size_t)i * 128 + h * 32);
        #pragma unroll
        for (int cch = 0; cch < 4; ++cch) {
            uint4 qv = qp[cch];
            unsigned int w_[4] = {qv.x, qv.y, qv.z, qv.w};
            #pragma unroll
            for (int dd = 0; dd < 4; ++dd) {
                qf[cch * 8 + dd * 2]     = __uint_as_float(w_[dd] << 16);
                qf[cch * 8 + dd * 2 + 1] = __uint_as_float(w_[dd] & 0xffff0000u);
            }
        }
    }

    float m = -INFINITY, l = 0.f;
    float accx = 0.f, accy = 0.f;

    for (int c0 = 0; c0 < deg; c0 += 16) {
        const int cnt = min(16, deg - c0);
        int col = 0;
        float s = -INFINITY;
        if (le < cnt) {
            col = colS[e0 + c0 + le];
            const uint4* kp = (const uint4*)(Kb + (size_t)col * 128 + h * 32);
            float dot = 0.f;
            #pragma unroll
            for (int cch = 0; cch < 4; ++cch) {
                uint4 kv = kp[cch];
                unsigned int w_[4] = {kv.x, kv.y, kv.z, kv.w};
                #pragma unroll
                for (int dd = 0; dd < 4; ++dd) {
                    dot += qf[cch * 8 + dd * 2]     * __uint_as_float(w_[dd] << 16);
                    dot += qf[cch * 8 + dd * 2 + 1] * __uint_as_float(w_[dd] & 0xffff0000u);
                }
            }
            s = dot * 0.17677669529663689f;   // 1/sqrt(32)
        }
        // per-head max over the 16 edge-lanes (lane stride 4)
        float sm = s;
        sm = fmaxf(sm, __shfl_xor(sm, 4));
        sm = fmaxf(sm, __shfl_xor(sm, 8));
        sm = fmaxf(sm, __shfl_xor(sm, 16));
        sm = fmaxf(sm, __shfl_xor(sm, 32));
        const float mn = fmaxf(m, sm);
        const float p = (le < cnt) ? __expf(s - mn) : 0.f;
        float ps = p;
        ps += __shfl_xor(ps, 4);
        ps += __shfl_xor(ps, 8);
        ps += __shfl_xor(ps, 16);
        ps += __shfl_xor(ps, 32);
        const float fac = __expf(m - mn);   // first chunk: exp(-inf)=0
        l = l * fac + ps;
        m = mn;
        // PV: rescale then accumulate; always 16 iterations (inactive lanes carry
        // col=0, p=0 -> adds 0*V[row 0], which stays L1-hot) so the compiler can
        // hoist all shuffles and keep 16 independent V-gathers in flight.
        const float facbc = __shfl(fac, g);   // head g's fac lives in lane g (le=0)
        accx *= facbc;
        accy *= facbc;
        #pragma unroll
        for (int e = 0; e < 16; ++e) {
            const int   cbc = __shfl(col, 4 * e);
            const float pbc = __shfl(p, 4 * e + g);
            const unsigned int v2 =
                *(const unsigned int*)(Vb + (size_t)cbc * 128 + 2 * lane);
            accx += pbc * __uint_as_float(v2 << 16);
            accy += pbc * __uint_as_float(v2 & 0xffff0000u);
        }
    }

    const float lf = __shfl(l, g);
    const float rinv = (lf > 0.f) ? 1.f / lf : 0.f;
    const unsigned int outw =
        ((unsigned int)f2bf(accy * rinv) << 16) | (unsigned int)f2bf(accx * rinv);
    *(unsigned int*)(xa + (size_t)i * 256 + 128 + 2 * lane) = outw;
}

// ---------------- MLP1 via MFMA + ReLU + LayerNorm -> bf16 h ----------------
__global__ __launch_bounds__(256) void gemm_mlp1_kernel(
        const unsigned short* __restrict__ xa, const unsigned short* __restrict__ w1f,
        const float* __restrict__ b1, const float* __restrict__ ln_g,
        const float* __restrict__ ln_b, unsigned short* __restrict__ hb) {
    const int wave = threadIdx.x >> 6, lane = threadIdx.x & 63;
    const int row0 = blockIdx.x * 64 + wave * 16;
    const int arow = row0 + (lane & 15);

    s16x8 a[8];
    const unsigned short* ap = xa + (size_t)arow * 256 + (lane >> 4) * 8;
    #pragma unroll
    for (int kk = 0; kk < 8; ++kk) a[kk] = *(const s16x8*)(ap + kk * 32);

    f32x4 acc[8];
    #pragma unroll
    for (int nt = 0; nt < 8; ++nt) acc[nt] = (f32x4){0.f, 0.f, 0.f, 0.f};

    const s16x8* wfv = (const s16x8*)w1f;
    #pragma unroll
    for (int nt = 0; nt < 8; ++nt) {
        #pragma unroll
        for (int kk = 0; kk < 8; ++kk) {
            s16x8 b = wfv[(nt * 8 + kk) * 64 + lane];
            acc[nt] = mfma_bf16(a[kk], b, acc[nt]);
        }
    }

    const int colb = lane & 15;
    #pragma unroll
    for (int nt = 0; nt < 8; ++nt) {
        float bias = b1[nt * 16 + colb];
        #pragma unroll
        for (int r = 0; r < 4; ++r) {
            float v = acc[nt][r] + bias;
            acc[nt][r] = v > 0.f ? v : 0.f;
        }
    }
    float mu[4], rs[4];
    #pragma unroll
    for (int r = 0; r < 4; ++r) {
        float s = 0.f, q = 0.f;
        #pragma unroll
        for (int nt = 0; nt < 8; ++nt) { float v = acc[nt][r]; s += v; q += v * v; }
        #pragma unroll
        for (int msk = 1; msk < 16; msk <<= 1) {
            s += __shfl_xor(s, msk, 16);
            q += __shfl_xor(q, msk, 16);
        }
        float m_ = s * (1.f / 128.f);
        float var = q * (1.f / 128.f) - m_ * m_;
        mu[r] = m_;
        rs[r] = rsqrtf(var + LN_EPS);
    }
    const int rbase = row0 + (lane >> 4) * 4;
    #pragma unroll
    for (int nt = 0; nt < 8; ++nt) {
        int col = nt * 16 + colb;
        float g = ln_g[col], bb = ln_b[col];
        #pragma unroll
        for (int r = 0; r < 4; ++r) {
            float h = (acc[nt][r] - mu[r]) * rs[r] * g + bb;
            hb[(size_t)(rbase + r) * 128 + col] = f2bf(h);
        }
    }
}

// ---------------- MLP2 via MFMA + bias + residual -> f32 out ----------------
__global__ __launch_bounds__(256) void gemm_mlp2_kernel(
        const unsigned short* __restrict__ hb, const unsigned short* __restrict__ w2f,
        const float* __restrict__ b2, const float* __restrict__ x,
        float* __restrict__ out) {
    const int wave = threadIdx.x >> 6, lane = threadIdx.x & 63;
    const int row0 = blockIdx.x * 64 + wave * 16;
    const int arow = row0 + (lane & 15);

    s16x8 a[4];
    const unsigned short* ap = hb + (size_t)arow * 128 + (lane >> 4) * 8;
    #pragma unroll
    for (int kk = 0; kk < 4; ++kk) a[kk] = *(const s16x8*)(ap + kk * 32);

    f32x4 acc[8];
    #pragma unroll
    for (int nt = 0; nt < 8; ++nt) acc[nt] = (f32x4){0.f, 0.f, 0.f, 0.f};

    const s16x8* wfv = (const s16x8*)w2f;
    #pragma unroll
    for (int nt = 0; nt < 8; ++nt) {
        #pragma unroll
        for (int kk = 0; kk < 4; ++kk) {
            s16x8 b = wfv[(nt * 4 + kk) * 64 + lane];
            acc[nt] = mfma_bf16(a[kk], b, acc[nt]);
        }
    }

    const int colb = lane & 15;
    const int rbase = row0 + (lane >> 4) * 4;
    #pragma unroll
    for (int nt = 0; nt < 8; ++nt) {
        int col = nt * 16 + colb;
        float bias = b2[col];
        #pragma unroll
        for (int r = 0; r < 4; ++r) {
            int row = rbase + r;
            if (row < NN)
                out[(size_t)row * 128 + col] = acc[nt][r] + bias + x[(size_t)row * 128 + col];
        }
    }
}

extern "C" void kernel_launch(void* const* d_in, const int* in_sizes, int n_in,
                              void* d_out, int out_size, void* d_ws, size_t ws_size,
                              hipStream_t stream) {
    const float* x    = (const float*)d_in[0];
    const void*  ei   = d_in[1];
    const float* Wq   = (const float*)d_in[2];
    const float* bq   = (const float*)d_in[3];
    const float* Wk   = (const float*)d_in[4];
    const float* bk   = (const float*)d_in[5];
    const float* Wv   = (const float*)d_in[6];
    const float* bv   = (const float*)d_in[7];
    const float* W1   = (const float*)d_in[8];
    const float* b1   = (const float*)d_in[9];
    const float* ln_g = (const float*)d_in[10];
    const float* ln_b = (const float*)d_in[11];
    const float* W2   = (const float*)d_in[12];
    const float* b2   = (const float*)d_in[13];
    float* out = (float*)d_out;

    char* ws = (char*)d_ws;
    size_t off = 0;
    auto alloc = [&](size_t bytes) {
        size_t o = off;
        off = (off + bytes + 255) & ~(size_t)255;
        return o;
    };
    size_t flag_o = alloc(sizeof(int));
    size_t rowi_o = alloc((size_t)EE * sizeof(int));
    size_t coli_o = alloc((size_t)EE * sizeof(int));
    size_t deg_o  = alloc((size_t)NN * sizeof(int));
    size_t cur_o  = alloc((size_t)NN * sizeof(int));
    size_t rs_o   = alloc((size_t)(NN + 1) * sizeof(int));
    size_t bsum_o = alloc((size_t)SCAN_NB * sizeof(int));
    size_t boff_o = alloc((size_t)SCAN_NB * sizeof(int));
    size_t colS_o = alloc((size_t)EE * sizeof(int));
    size_t xa_o   = alloc((size_t)ROWS_PAD * 256 * sizeof(unsigned short));
    size_t wf_o   = alloc((size_t)98304 * sizeof(unsigned short));
    size_t Qb_o   = alloc((size_t)ROWS_PAD * 128 * sizeof(unsigned short));
    size_t Kb_o   = alloc((size_t)ROWS_PAD * 128 * sizeof(unsigned short));
    size_t Vb_o   = alloc((size_t)ROWS_PAD * 128 * sizeof(unsigned short));
    size_t hb_o   = Qb_o;  // h reuses Q (dead after attn)

    int* flag   = (int*)(ws + flag_o);
    int* rowi   = (int*)(ws + rowi_o);
    int* coli   = (int*)(ws + coli_o);
    int* deg    = (int*)(ws + deg_o);
    int* cursor = (int*)(ws + cur_o);
    int* rstart = (int*)(ws + rs_o);
    int* bsum   = (int*)(ws + bsum_o);
    int* boff   = (int*)(ws + boff_o);
    int* colS   = (int*)(ws + colS_o);
    unsigned short* xa = (unsigned short*)(ws + xa_o);
    unsigned short* wf = (unsigned short*)(ws + wf_o);
    unsigned short* Qb = (unsigned short*)(ws + Qb_o);
    unsigned short* Kb = (unsigned short*)(ws + Kb_o);
    unsigned short* Vb = (unsigned short*)(ws + Vb_o);
    unsigned short* hb = (unsigned short*)(ws + hb_o);

    hipMemsetAsync(ws + deg_o, 0, (size_t)NN * sizeof(int), stream);

    detect_idx_kernel<<<1, 64, 0, stream>>>((const unsigned int*)ei, flag);
    convert_hist_kernel<<<(EE + 255) / 256, 256, 0, stream>>>(ei, flag, rowi, coli, deg);
    scan_a_kernel<<<SCAN_NB, 512, 0, stream>>>(deg, bsum);
    scan_b_kernel<<<1, 64, 0, stream>>>(bsum, boff);
    scan_c_kernel<<<SCAN_NB, 512, 0, stream>>>(deg, boff, rstart, cursor);
    scatter_kernel<<<(EE + 255) / 256, 256, 0, stream>>>(rowi, coli, cursor, colS);

    pack_kernel<<<(PACKX_T + 98304 + 255) / 256, 256, 0, stream>>>(
        x, Wq, Wk, Wv, W1, W2, xa, wf);

    gemm_qkv_kernel<<<ROWS_PAD / 64, 256, 0, stream>>>(xa, wf, bq, bk, bv, Qb, Kb, Vb);

    attn_kernel<<<(NN + 3) / 4, 256, 0, stream>>>(Qb, Kb, Vb, rstart, colS, xa);

    gemm_mlp1_kernel<<<ROWS_PAD / 64, 256, 0, stream>>>(xa, wf + 49152, b1, ln_g, ln_b, hb);

    gemm_mlp2_kernel<<<ROWS_PAD / 64, 256, 0, stream>>>(hb, wf + 81920, b2, x, out);
}

// Round 6
// 224.128 us; speedup vs baseline: 4.2364x; 1.0407x over previous
//
#include <hip/hip_runtime.h>
#include <hip/hip_bf16.h>

#define NN 50000
#define HH 128
#define NHEAD 4
#define HD 32
#define EE 800000
#define LN_EPS 1e-5f
#define ROWS_PAD 50048   // 782 * 64
#define SCAN_NB 98       // ceil(NN/512)

typedef __bf16 bf16x8 __attribute__((ext_vector_type(8)));
typedef short  s16x8  __attribute__((ext_vector_type(8)));
typedef float  f32x4  __attribute__((ext_vector_type(4)));

__device__ __forceinline__ f32x4 mfma_bf16(s16x8 a, s16x8 b, f32x4 c) {
    return __builtin_amdgcn_mfma_f32_16x16x32_bf16((bf16x8)a, (bf16x8)b, c, 0, 0, 0);
}

__device__ __forceinline__ unsigned short f2bf(float f) {
    union { float f; unsigned int u; } v; v.f = f;
    unsigned int u = v.u + 0x7FFFu + ((v.u >> 16) & 1u);  // RNE
    return (unsigned short)(u >> 16);
}
__device__ __forceinline__ float bf2f(unsigned short h) {
    union { unsigned int u; float f; } v; v.u = ((unsigned int)h) << 16;
    return v.f;
}
__device__ __forceinline__ float bflo(unsigned int w) { return __uint_as_float(w << 16); }
__device__ __forceinline__ float bfhi(unsigned int w) { return __uint_as_float(w & 0xffff0000u); }

// ---------------- index dtype probe ----------------
__global__ void detect_idx_kernel(const unsigned int* __restrict__ buf, int* __restrict__ flag) {
    if (blockIdx.x == 0 && threadIdx.x == 0) {
        int is64 = 1;
        for (int i = 0; i < 64; ++i) {
            if (buf[2 * i + 1] != 0u) { is64 = 0; break; }
        }
        *flag = is64;
    }
}

// 2 edges per thread, vectorized loads
__global__ void convert_hist_kernel(const void* __restrict__ ei, const int* __restrict__ flag,
                                    int* __restrict__ rowi, int* __restrict__ coli,
                                    int* __restrict__ deg) {
    int i = (blockIdx.x * blockDim.x + threadIdx.x) * 2;
    if (i >= EE) return;
    int r0, r1, c0, c1;
    if (*flag) {
        const longlong2* pr = (const longlong2*)((const long long*)ei + i);
        const longlong2* pc = (const longlong2*)((const long long*)ei + EE + i);
        longlong2 rv = *pr, cv = *pc;
        r0 = (int)rv.x; r1 = (int)rv.y;
        c0 = (int)cv.x; c1 = (int)cv.y;
    } else {
        const int2* pr = (const int2*)((const int*)ei + i);
        const int2* pc = (const int2*)((const int*)ei + EE + i);
        int2 rv = *pr, cv = *pc;
        r0 = rv.x; r1 = rv.y;
        c0 = cv.x; c1 = cv.y;
    }
    *(int2*)(rowi + i) = make_int2(r0, r1);
    *(int2*)(coli + i) = make_int2(c0, c1);
    atomicAdd(&deg[r0], 1);
    atomicAdd(&deg[r1], 1);
}

// ---------------- multi-block exclusive scan of degrees ----------------
__global__ __launch_bounds__(512) void scan_a_kernel(const int* __restrict__ deg,
                                                     int* __restrict__ bsum) {
    __shared__ int red[8];
    const int t = threadIdx.x;
    const int gid = blockIdx.x * 512 + t;
    int v = (gid < NN) ? deg[gid] : 0;
    #pragma unroll
    for (int o = 1; o < 64; o <<= 1) v += __shfl_xor(v, o);
    if ((t & 63) == 0) red[t >> 6] = v;
    __syncthreads();
    if (t == 0) {
        int s = 0;
        #pragma unroll
        for (int k = 0; k < 8; ++k) s += red[k];
        bsum[blockIdx.x] = s;
    }
}

__global__ void scan_b_kernel(const int* __restrict__ bsum, int* __restrict__ boff) {
    const int lane = threadIdx.x;  // 64 threads
    const int i0 = lane * 2, i1 = lane * 2 + 1;
    int a = (i0 < SCAN_NB) ? bsum[i0] : 0;
    int b = (i1 < SCAN_NB) ? bsum[i1] : 0;
    int incl = a + b;
    const int own = incl;
    #pragma unroll
    for (int o = 1; o < 64; o <<= 1) {
        int u = __shfl_up(incl, o);
        if (lane >= o) incl += u;
    }
    int excl = incl - own;
    if (i0 < SCAN_NB) boff[i0] = excl;
    if (i1 < SCAN_NB) boff[i1] = excl + a;
}

__global__ __launch_bounds__(512) void scan_c_kernel(const int* __restrict__ deg,
                                                     const int* __restrict__ boff,
                                                     int* __restrict__ rstart,
                                                     int* __restrict__ cursor) {
    __shared__ int wsum[8];
    const int t = threadIdx.x;
    const int gid = blockIdx.x * 512 + t;
    const int lane = t & 63, w = t >> 6;
    int v = (gid < NN) ? deg[gid] : 0;
    int incl = v;
    #pragma unroll
    for (int o = 1; o < 64; o <<= 1) {
        int u = __shfl_up(incl, o);
        if (lane >= o) incl += u;
    }
    if (lane == 63) wsum[w] = incl;
    __syncthreads();
    int woff = 0;
    for (int k = 0; k < w; ++k) woff += wsum[k];
    int excl = boff[blockIdx.x] + woff + incl - v;
    if (gid < NN) { rstart[gid] = excl; cursor[gid] = excl; }
    if (gid == 0) rstart[NN] = EE;
}

__global__ void scatter_kernel(const int* __restrict__ rowi, const int* __restrict__ coli,
                               int* __restrict__ cursor, int* __restrict__ colS) {
    int i = blockIdx.x * blockDim.x + threadIdx.x;
    if (i >= EE) return;
    int pos = atomicAdd(&cursor[rowi[i]], 1);
    colS[pos] = coli[i];
}

// ---------------- pack weights into MFMA b-fragment order ----------------
// fragment element index: (((ntile*KSTEPS + kk)*64 + lane)*8 + j)
// value = W[kk*32 + (lane>>4)*8 + j][ntile*16 + (lane&15)]
__global__ void pack_w_kernel(const float* __restrict__ Wq, const float* __restrict__ Wk,
                              const float* __restrict__ Wv, const float* __restrict__ W1,
                              const float* __restrict__ W2, unsigned short* __restrict__ wf) {
    int i = blockIdx.x * blockDim.x + threadIdx.x;
    if (i >= 98304) return;
    float val;
    if (i < 49152) {                      // QKV: ntiles=24, ksteps=4, K=128
        int j = i & 7, lane = (i >> 3) & 63, kk = (i >> 9) & 3, nt = i >> 11;
        int k = kk * 32 + (lane >> 4) * 8 + j;
        int n = nt * 16 + (lane & 15);    // 0..383
        const float* W = (n < 128) ? Wq : ((n < 256) ? Wk : Wv);
        val = W[k * HH + (n & 127)];
    } else if (i < 81920) {               // W1: ntiles=8, ksteps=8, K=256
        int local = i - 49152;
        int j = local & 7, lane = (local >> 3) & 63, kk = (local >> 9) & 7, nt = local >> 12;
        int k = kk * 32 + (lane >> 4) * 8 + j;
        int n = nt * 16 + (lane & 15);
        val = W1[k * HH + n];
    } else {                              // W2: ntiles=8, ksteps=4, K=128
        int local = i - 81920;
        int j = local & 7, lane = (local >> 3) & 63, kk = (local >> 9) & 3, nt = local >> 11;
        int k = kk * 32 + (lane >> 4) * 8 + j;
        int n = nt * 16 + (lane & 15);
        val = W2[k * HH + n];
    }
    wf[i] = f2bf(val);
}

// ---------------- fused x-pack + QKV GEMM via MFMA ----------------
// reads x f32, emits bf16 copy into xa left half, computes Q/K/V
__global__ __launch_bounds__(256) void qkvx_kernel(
        const float* __restrict__ x, const unsigned short* __restrict__ wf,
        const float* __restrict__ bq, const float* __restrict__ bk, const float* __restrict__ bv,
        unsigned short* __restrict__ xa,
        unsigned short* __restrict__ Qb, unsigned short* __restrict__ Kb,
        unsigned short* __restrict__ Vb) {
    const int wave = threadIdx.x >> 6, lane = threadIdx.x & 63;
    const int row0 = blockIdx.x * 64 + wave * 16;
    const int arow = row0 + (lane & 15);
    const int kbase = (lane >> 4) * 8;

    s16x8 a[4];
    if (arow < NN) {
        const float* xp = x + (size_t)arow * HH + kbase;
        #pragma unroll
        for (int kk = 0; kk < 4; ++kk) {
            float4 f0 = *(const float4*)(xp + kk * 32);
            float4 f1 = *(const float4*)(xp + kk * 32 + 4);
            s16x8 av;
            av[0] = (short)f2bf(f0.x); av[1] = (short)f2bf(f0.y);
            av[2] = (short)f2bf(f0.z); av[3] = (short)f2bf(f0.w);
            av[4] = (short)f2bf(f1.x); av[5] = (short)f2bf(f1.y);
            av[6] = (short)f2bf(f1.z); av[7] = (short)f2bf(f1.w);
            a[kk] = av;
            *(s16x8*)(xa + (size_t)arow * 256 + kbase + kk * 32) = av;
        }
    } else {
        #pragma unroll
        for (int kk = 0; kk < 4; ++kk) a[kk] = (s16x8)0;
    }

    f32x4 acc[24];
    #pragma unroll
    for (int nt = 0; nt < 24; ++nt) acc[nt] = (f32x4){0.f, 0.f, 0.f, 0.f};

    const s16x8* wfv = (const s16x8*)wf;
    #pragma unroll
    for (int nt = 0; nt < 24; ++nt) {
        #pragma unroll
        for (int kk = 0; kk < 4; ++kk) {
            s16x8 b = wfv[(nt * 4 + kk) * 64 + lane];
            acc[nt] = mfma_bf16(a[kk], b, acc[nt]);
        }
    }

    const int colb = lane & 15;
    const int rbase = row0 + (lane >> 4) * 4;
    #pragma unroll
    for (int nt = 0; nt < 24; ++nt) {
        const int mtx = nt >> 3;                  // 0:Q 1:K 2:V
        const int nc = (nt & 7) * 16 + colb;      // 0..127
        const float* bias_p = (mtx == 0) ? bq : ((mtx == 1) ? bk : bv);
        unsigned short* O = (mtx == 0) ? Qb : ((mtx == 1) ? Kb : Vb);
        float bias = bias_p[nc];
        #pragma unroll
        for (int r = 0; r < 4; ++r)
            O[(size_t)(rbase + r) * 128 + nc] = f2bf(acc[nt][r] + bias);
    }
}

// ---------------- fused per-node attention: one wave per node ----------------
// score phase: lane = local_edge*4 + head (lane-local 32-dim dot)
// PV phase: half = lane>>5 handles edges of that parity; lane owns dims 4*sl..4*sl+3
__global__ __launch_bounds__(256) void attn_kernel(
        const unsigned short* __restrict__ Qb, const unsigned short* __restrict__ Kb,
        const unsigned short* __restrict__ Vb, const int* __restrict__ rstart,
        const int* __restrict__ colS, unsigned short* __restrict__ xa) {
    const int wave = threadIdx.x >> 6;
    const int lane = threadIdx.x & 63;
    const int i = blockIdx.x * 4 + wave;
    if (i >= NN) return;
    const int h = lane & 3;       // head (score phase)
    const int le = lane >> 2;     // local edge 0..15 (score phase)
    const int half = lane >> 5;   // PV: edge parity
    const int sl = lane & 31;     // PV: dim group (4 dims)
    const int g2 = sl >> 3;       // PV: head of owned dims
    const int e0 = rstart[i], e1 = rstart[i + 1];
    const int deg = e1 - e0;

    // unpack this head's Q slice into 32 f32 regs
    float qf[32];
    {
        const uint4* qp = (const uint4*)(Qb + (size_t)i * 128 + h * 32);
        #pragma unroll
        for (int cch = 0; cch < 4; ++cch) {
            uint4 qv = qp[cch];
            unsigned int w_[4] = {qv.x, qv.y, qv.z, qv.w};
            #pragma unroll
            for (int dd = 0; dd < 4; ++dd) {
                qf[cch * 8 + dd * 2]     = bflo(w_[dd]);
                qf[cch * 8 + dd * 2 + 1] = bfhi(w_[dd]);
            }
        }
    }

    float m = -INFINITY, l = 0.f;
    float acc0 = 0.f, acc1 = 0.f, acc2 = 0.f, acc3 = 0.f;

    for (int c0 = 0; c0 < deg; c0 += 16) {
        const int cnt = min(16, deg - c0);
        int col = 0;
        float s = -INFINITY;
        if (le < cnt) {
            col = colS[e0 + c0 + le];
            const uint4* kp = (const uint4*)(Kb + (size_t)col * 128 + h * 32);
            float dot = 0.f;
            #pragma unroll
            for (int cch = 0; cch < 4; ++cch) {
                uint4 kv = kp[cch];
                unsigned int w_[4] = {kv.x, kv.y, kv.z, kv.w};
                #pragma unroll
                for (int dd = 0; dd < 4; ++dd) {
                    dot += qf[cch * 8 + dd * 2]     * bflo(w_[dd]);
                    dot += qf[cch * 8 + dd * 2 + 1] * bfhi(w_[dd]);
                }
            }
            s = dot * 0.17677669529663689f;   // 1/sqrt(32)
        }
        // per-head reduce over the 16 edge-lanes (lane stride 4)
        float sm = s;
        sm = fmaxf(sm, __shfl_xor(sm, 4));
        sm = fmaxf(sm, __shfl_xor(sm, 8));
        sm = fmaxf(sm, __shfl_xor(sm, 16));
        sm = fmaxf(sm, __shfl_xor(sm, 32));
        const float mn = fmaxf(m, sm);
        const float p = (le < cnt) ? __expf(s - mn) : 0.f;
        float ps = p;
        ps += __shfl_xor(ps, 4);
        ps += __shfl_xor(ps, 8);
        ps += __shfl_xor(ps, 16);
        ps += __shfl_xor(ps, 32);
        const float fac = __expf(m - mn);   // first chunk: exp(-inf)=0
        l = l * fac + ps;
        m = mn;
        // PV: each half handles 8 edges of its parity; 4 dims per lane (dwordx2)
        const float facbc = __shfl(fac, g2);
        acc0 *= facbc; acc1 *= facbc; acc2 *= facbc; acc3 *= facbc;
        #pragma unroll
        for (int e2 = 0; e2 < 8; ++e2) {
            const int e = 2 * e2 + half;
            const int   cbc = __shfl(col, 4 * e);
            const float pbc = __shfl(p, 4 * e + g2);
            const uint2 v2 = *(const uint2*)(Vb + (size_t)cbc * 128 + 4 * sl);
            acc0 += pbc * bflo(v2.x);
            acc1 += pbc * bfhi(v2.x);
            acc2 += pbc * bflo(v2.y);
            acc3 += pbc * bfhi(v2.y);
        }
    }

    // combine the two edge-parity halves
    acc0 += __shfl_xor(acc0, 32);
    acc1 += __shfl_xor(acc1, 32);
    acc2 += __shfl_xor(acc2, 32);
    acc3 += __shfl_xor(acc3, 32);
    const float lf = __shfl(l, g2);
    const float rinv = (lf > 0.f) ? 1.f / lf : 0.f;
    if (half == 0) {
        uint2 o;
        o.x = ((unsigned int)f2bf(acc1 * rinv) << 16) | (unsigned int)f2bf(acc0 * rinv);
        o.y = ((unsigned int)f2bf(acc3 * rinv) << 16) | (unsigned int)f2bf(acc2 * rinv);
        *(uint2*)(xa + (size_t)i * 256 + 128 + 4 * sl) = o;
    }
}

// ---------------- MLP1 via MFMA + ReLU + LayerNorm -> bf16 h ----------------
__global__ __launch_bounds__(256) void gemm_mlp1_kernel(
        const unsigned short* __restrict__ xa, const unsigned short* __restrict__ w1f,
        const float* __restrict__ b1, const float* __restrict__ ln_g,
        const float* __restrict__ ln_b, unsigned short* __restrict__ hb) {
    const int wave = threadIdx.x >> 6, lane = threadIdx.x & 63;
    const int row0 = blockIdx.x * 64 + wave * 16;
    const int arow = row0 + (lane & 15);

    s16x8 a[8];
    const unsigned short* ap = xa + (size_t)arow * 256 + (lane >> 4) * 8;
    #pragma unroll
    for (int kk = 0; kk < 8; ++kk) a[kk] = *(const s16x8*)(ap + kk * 32);

    f32x4 acc[8];
    #pragma unroll
    for (int nt = 0; nt < 8; ++nt) acc[nt] = (f32x4){0.f, 0.f, 0.f, 0.f};

    const s16x8* wfv = (const s16x8*)w1f;
    #pragma unroll
    for (int nt = 0; nt < 8; ++nt) {
        #pragma unroll
        for (int kk = 0; kk < 8; ++kk) {
            s16x8 b = wfv[(nt * 8 + kk) * 64 + lane];
            acc[nt] = mfma_bf16(a[kk], b, acc[nt]);
        }
    }

    const int colb = lane & 15;
    #pragma unroll
    for (int nt = 0; nt < 8; ++nt) {
        float bias = b1[nt * 16 + colb];
        #pragma unroll
        for (int r = 0; r < 4; ++r) {
            float v = acc[nt][r] + bias;
            acc[nt][r] = v > 0.f ? v : 0.f;
        }
    }
    float mu[4], rs[4];
    #pragma unroll
    for (int r = 0; r < 4; ++r) {
        float s = 0.f, q = 0.f;
        #pragma unroll
        for (int nt = 0; nt < 8; ++nt) { float v = acc[nt][r]; s += v; q += v * v; }
        #pragma unroll
        for (int msk = 1; msk < 16; msk <<= 1) {
            s += __shfl_xor(s, msk, 16);
            q += __shfl_xor(q, msk, 16);
        }
        float m_ = s * (1.f / 128.f);
        float var = q * (1.f / 128.f) - m_ * m_;
        mu[r] = m_;
        rs[r] = rsqrtf(var + LN_EPS);
    }
    const int rbase = row0 + (lane >> 4) * 4;
    #pragma unroll
    for (int nt = 0; nt < 8; ++nt) {
        int col = nt * 16 + colb;
        float g = ln_g[col], bb = ln_b[col];
        #pragma unroll
        for (int r = 0; r < 4; ++r) {
            float h = (acc[nt][r] - mu[r]) * rs[r] * g + bb;
            hb[(size_t)(rbase + r) * 128 + col] = f2bf(h);
        }
    }
}

// ---------------- MLP2 via MFMA + bias + residual (bf16 x from xa) -> f32 out ----------------
__global__ __launch_bounds__(256) void gemm_mlp2_kernel(
        const unsigned short* __restrict__ hb, const unsigned short* __restrict__ w2f,
        const float* __restrict__ b2, const unsigned short* __restrict__ xa,
        float* __restrict__ out) {
    const int wave = threadIdx.x >> 6, lane = threadIdx.x & 63;
    const int row0 = blockIdx.x * 64 + wave * 16;
    const int arow = row0 + (lane & 15);

    s16x8 a[4];
    const unsigned short* ap = hb + (size_t)arow * 128 + (lane >> 4) * 8;
    #pragma unroll
    for (int kk = 0; kk < 4; ++kk) a[kk] = *(const s16x8*)(ap + kk * 32);

    f32x4 acc[8];
    #pragma unroll
    for (int nt = 0; nt < 8; ++nt) acc[nt] = (f32x4){0.f, 0.f, 0.f, 0.f};

    const s16x8* wfv = (const s16x8*)w2f;
    #pragma unroll
    for (int nt = 0; nt < 8; ++nt) {
        #pragma unroll
        for (int kk = 0; kk < 4; ++kk) {
            s16x8 b = wfv[(nt * 4 + kk) * 64 + lane];
            acc[nt] = mfma_bf16(a[kk], b, acc[nt]);
        }
    }

    const int colb = lane & 15;
    const int rbase = row0 + (lane >> 4) * 4;
    #pragma unroll
    for (int nt = 0; nt < 8; ++nt) {
        int col = nt * 16 + colb;
        float bias = b2[col];
        #pragma unroll
        for (int r = 0; r < 4; ++r) {
            int row = rbase + r;
            if (row < NN)
                out[(size_t)row * 128 + col] =
                    acc[nt][r] + bias + bf2f(xa[(size_t)row * 256 + col]);
        }
    }
}

extern "C" void kernel_launch(void* const* d_in, const int* in_sizes, int n_in,
                              void* d_out, int out_size, void* d_ws, size_t ws_size,
                              hipStream_t stream) {
    const float* x    = (const float*)d_in[0];
    const void*  ei   = d_in[1];
    const float* Wq   = (const float*)d_in[2];
    const float* bq   = (const float*)d_in[3];
    const float* Wk   = (const float*)d_in[4];
    const float* bk   = (const float*)d_in[5];
    const float* Wv   = (const float*)d_in[6];
    const float* bv   = (const float*)d_in[7];
    const float* W1   = (const float*)d_in[8];
    const float* b1   = (const float*)d_in[9];
    const float* ln_g = (const float*)d_in[10];
    const float* ln_b = (const float*)d_in[11];
    const float* W2   = (const float*)d_in[12];
    const float* b2   = (const float*)d_in[13];
    float* out = (float*)d_out;

    char* ws = (char*)d_ws;
    size_t off = 0;
    auto alloc = [&](size_t bytes) {
        size_t o = off;
        off = (off + bytes + 255) & ~(size_t)255;
        return o;
    };
    size_t flag_o = alloc(sizeof(int));
    size_t rowi_o = alloc((size_t)EE * sizeof(int));
    size_t coli_o = alloc((size_t)EE * sizeof(int));
    size_t deg_o  = alloc((size_t)NN * sizeof(int));
    size_t cur_o  = alloc((size_t)NN * sizeof(int));
    size_t rs_o   = alloc((size_t)(NN + 1) * sizeof(int));
    size_t bsum_o = alloc((size_t)SCAN_NB * sizeof(int));
    size_t boff_o = alloc((size_t)SCAN_NB * sizeof(int));
    size_t colS_o = alloc((size_t)EE * sizeof(int));
    size_t xa_o   = alloc((size_t)ROWS_PAD * 256 * sizeof(unsigned short));
    size_t wf_o   = alloc((size_t)98304 * sizeof(unsigned short));
    size_t Qb_o   = alloc((size_t)ROWS_PAD * 128 * sizeof(unsigned short));
    size_t Kb_o   = alloc((size_t)ROWS_PAD * 128 * sizeof(unsigned short));
    size_t Vb_o   = alloc((size_t)ROWS_PAD * 128 * sizeof(unsigned short));
    size_t hb_o   = Qb_o;  // h reuses Q (dead after attn)

    int* flag   = (int*)(ws + flag_o);
    int* rowi   = (int*)(ws + rowi_o);
    int* coli   = (int*)(ws + coli_o);
    int* deg    = (int*)(ws + deg_o);
    int* cursor = (int*)(ws + cur_o);
    int* rstart = (int*)(ws + rs_o);
    int* bsum   = (int*)(ws + bsum_o);
    int* boff   = (int*)(ws + boff_o);
    int* colS   = (int*)(ws + colS_o);
    unsigned short* xa = (unsigned short*)(ws + xa_o);
    unsigned short* wf = (unsigned short*)(ws + wf_o);
    unsigned short* Qb = (unsigned short*)(ws + Qb_o);
    unsigned short* Kb = (unsigned short*)(ws + Kb_o);
    unsigned short* Vb = (unsigned short*)(ws + Vb_o);
    unsigned short* hb = (unsigned short*)(ws + hb_o);

    hipMemsetAsync(ws + deg_o, 0, (size_t)NN * sizeof(int), stream);

    detect_idx_kernel<<<1, 64, 0, stream>>>((const unsigned int*)ei, flag);
    convert_hist_kernel<<<(EE / 2 + 255) / 256, 256, 0, stream>>>(ei, flag, rowi, coli, deg);
    scan_a_kernel<<<SCAN_NB, 512, 0, stream>>>(deg, bsum);
    scan_b_kernel<<<1, 64, 0, stream>>>(bsum, boff);
    scan_c_kernel<<<SCAN_NB, 512, 0, stream>>>(deg, boff, rstart, cursor);
    scatter_kernel<<<(EE + 255) / 256, 256, 0, stream>>>(rowi, coli, cursor, colS);

    pack_w_kernel<<<98304 / 256, 256, 0, stream>>>(Wq, Wk, Wv, W1, W2, wf);

    qkvx_kernel<<<ROWS_PAD / 64, 256, 0, stream>>>(x, wf, bq, bk, bv, xa, Qb, Kb, Vb);

    attn_kernel<<<(NN + 3) / 4, 256, 0, stream>>>(Qb, Kb, Vb, rstart, colS, xa);

    gemm_mlp1_kernel<<<ROWS_PAD / 64, 256, 0, stream>>>(xa, wf + 49152, b1, ln_g, ln_b, hb);

    gemm_mlp2_kernel<<<ROWS_PAD / 64, 256, 0, stream>>>(hb, wf + 81920, b2, xa, out);
}

// Round 7
// 193.834 us; speedup vs baseline: 4.8985x; 1.1563x over previous
//
#include <hip/hip_runtime.h>
#include <hip/hip_bf16.h>

#define NN 50000
#define HH 128
#define NHEAD 4
#define HD 32
#define EE 800000
#define LN_EPS 1e-5f
#define ROWS_PAD 50048   // 782 * 64
#define SCAN_NB 98       // ceil(NN/512)

typedef __bf16 bf16x8 __attribute__((ext_vector_type(8)));
typedef short  s16x8  __attribute__((ext_vector_type(8)));
typedef float  f32x4  __attribute__((ext_vector_type(4)));

__device__ __forceinline__ f32x4 mfma_bf16(s16x8 a, s16x8 b, f32x4 c) {
    return __builtin_amdgcn_mfma_f32_16x16x32_bf16((bf16x8)a, (bf16x8)b, c, 0, 0, 0);
}

__device__ __forceinline__ unsigned short f2bf(float f) {
    union { float f; unsigned int u; } v; v.f = f;
    unsigned int u = v.u + 0x7FFFu + ((v.u >> 16) & 1u);  // RNE
    return (unsigned short)(u >> 16);
}
__device__ __forceinline__ float bf2f(unsigned short h) {
    union { unsigned int u; float f; } v; v.u = ((unsigned int)h) << 16;
    return v.f;
}
__device__ __forceinline__ float bflo(unsigned int w) { return __uint_as_float(w << 16); }
__device__ __forceinline__ float bfhi(unsigned int w) { return __uint_as_float(w & 0xffff0000u); }

// ---------------- index dtype probe ----------------
__global__ void detect_idx_kernel(const unsigned int* __restrict__ buf, int* __restrict__ flag) {
    if (blockIdx.x == 0 && threadIdx.x == 0) {
        int is64 = 1;
        for (int i = 0; i < 64; ++i) {
            if (buf[2 * i + 1] != 0u) { is64 = 0; break; }
        }
        *flag = is64;
    }
}

// histogram destination degrees + record each edge's rank within its segment
// (the atomicAdd return value IS the rank -> scatter needs no atomics)
__global__ void hist_kernel(const void* __restrict__ ei, const int* __restrict__ flag,
                            int* __restrict__ deg, int* __restrict__ rank) {
    int i = (blockIdx.x * blockDim.x + threadIdx.x) * 2;
    if (i >= EE) return;
    int r0, r1;
    if (*flag) {
        longlong2 rv = *(const longlong2*)((const long long*)ei + i);
        r0 = (int)rv.x; r1 = (int)rv.y;
    } else {
        int2 rv = *(const int2*)((const int*)ei + i);
        r0 = rv.x; r1 = rv.y;
    }
    int ra = atomicAdd(&deg[r0], 1);
    int rb = atomicAdd(&deg[r1], 1);
    *(int2*)(rank + i) = make_int2(ra, rb);
}

// ---------------- scan of degrees: block reduce, then local scan w/ inline top scan ----------------
__global__ __launch_bounds__(512) void scan_a_kernel(const int* __restrict__ deg,
                                                     int* __restrict__ bsum) {
    __shared__ int red[8];
    const int t = threadIdx.x;
    const int gid = blockIdx.x * 512 + t;
    int v = (gid < NN) ? deg[gid] : 0;
    #pragma unroll
    for (int o = 1; o < 64; o <<= 1) v += __shfl_xor(v, o);
    if ((t & 63) == 0) red[t >> 6] = v;
    __syncthreads();
    if (t == 0) {
        int s = 0;
        #pragma unroll
        for (int k = 0; k < 8; ++k) s += red[k];
        bsum[blockIdx.x] = s;
    }
}

__global__ __launch_bounds__(512) void scan_c_kernel(const int* __restrict__ deg,
                                                     const int* __restrict__ bsum,
                                                     int* __restrict__ rstart) {
    __shared__ int wsum[8];
    __shared__ int blockoff;
    const int t = threadIdx.x;
    const int gid = blockIdx.x * 512 + t;
    const int lane = t & 63, w = t >> 6;
    // wave 0: prefix over preceding block sums
    if (t < 64) {
        int s = 0;
        for (int k = t; k < blockIdx.x; k += 64) s += bsum[k];
        #pragma unroll
        for (int o = 1; o < 64; o <<= 1) s += __shfl_xor(s, o);
        if (t == 0) blockoff = s;
    }
    int v = (gid < NN) ? deg[gid] : 0;
    int incl = v;
    #pragma unroll
    for (int o = 1; o < 64; o <<= 1) {
        int u = __shfl_up(incl, o);
        if (lane >= o) incl += u;
    }
    if (lane == 63) wsum[w] = incl;
    __syncthreads();
    int woff = 0;
    for (int k = 0; k < w; ++k) woff += wsum[k];
    int excl = blockoff + woff + incl - v;
    if (gid < NN) rstart[gid] = excl;
    if (gid == 0) rstart[NN] = EE;
}

// atomic-free scatter using precomputed ranks
__global__ void scatter_kernel(const void* __restrict__ ei, const int* __restrict__ flag,
                               const int* __restrict__ rank, const int* __restrict__ rstart,
                               int* __restrict__ colS) {
    int i = (blockIdx.x * blockDim.x + threadIdx.x) * 2;
    if (i >= EE) return;
    int r0, r1, c0, c1;
    if (*flag) {
        longlong2 rv = *(const longlong2*)((const long long*)ei + i);
        longlong2 cv = *(const longlong2*)((const long long*)ei + EE + i);
        r0 = (int)rv.x; r1 = (int)rv.y;
        c0 = (int)cv.x; c1 = (int)cv.y;
    } else {
        int2 rv = *(const int2*)((const int*)ei + i);
        int2 cv = *(const int2*)((const int*)ei + EE + i);
        r0 = rv.x; r1 = rv.y;
        c0 = cv.x; c1 = cv.y;
    }
    int2 rk = *(const int2*)(rank + i);
    colS[rstart[r0] + rk.x] = c0;
    colS[rstart[r1] + rk.y] = c1;
}

// ---------------- pack weights into MFMA b-fragment order ----------------
// fragment element index: (((ntile*KSTEPS + kk)*64 + lane)*8 + j)
// value = W[kk*32 + (lane>>4)*8 + j][ntile*16 + (lane&15)]
__global__ void pack_w_kernel(const float* __restrict__ Wq, const float* __restrict__ Wk,
                              const float* __restrict__ Wv, const float* __restrict__ W1,
                              const float* __restrict__ W2, unsigned short* __restrict__ wf) {
    int i = blockIdx.x * blockDim.x + threadIdx.x;
    if (i >= 98304) return;
    float val;
    if (i < 49152) {                      // QKV: ntiles=24, ksteps=4, K=128
        int j = i & 7, lane = (i >> 3) & 63, kk = (i >> 9) & 3, nt = i >> 11;
        int k = kk * 32 + (lane >> 4) * 8 + j;
        int n = nt * 16 + (lane & 15);    // 0..383
        const float* W = (n < 128) ? Wq : ((n < 256) ? Wk : Wv);
        val = W[k * HH + (n & 127)];
    } else if (i < 81920) {               // W1: ntiles=8, ksteps=8, K=256
        int local = i - 49152;
        int j = local & 7, lane = (local >> 3) & 63, kk = (local >> 9) & 7, nt = local >> 12;
        int k = kk * 32 + (lane >> 4) * 8 + j;
        int n = nt * 16 + (lane & 15);
        val = W1[k * HH + n];
    } else {                              // W2: ntiles=8, ksteps=4, K=128
        int local = i - 81920;
        int j = local & 7, lane = (local >> 3) & 63, kk = (local >> 9) & 3, nt = local >> 11;
        int k = kk * 32 + (lane >> 4) * 8 + j;
        int n = nt * 16 + (lane & 15);
        val = W2[k * HH + n];
    }
    wf[i] = f2bf(val);
}

// ---------------- fused x-pack + QKV GEMM via MFMA ----------------
__global__ __launch_bounds__(256) void qkvx_kernel(
        const float* __restrict__ x, const unsigned short* __restrict__ wf,
        const float* __restrict__ bq, const float* __restrict__ bk, const float* __restrict__ bv,
        unsigned short* __restrict__ xa,
        unsigned short* __restrict__ Qb, unsigned short* __restrict__ Kb,
        unsigned short* __restrict__ Vb) {
    const int wave = threadIdx.x >> 6, lane = threadIdx.x & 63;
    const int row0 = blockIdx.x * 64 + wave * 16;
    const int arow = row0 + (lane & 15);
    const int kbase = (lane >> 4) * 8;

    s16x8 a[4];
    if (arow < NN) {
        const float* xp = x + (size_t)arow * HH + kbase;
        #pragma unroll
        for (int kk = 0; kk < 4; ++kk) {
            float4 f0 = *(const float4*)(xp + kk * 32);
            float4 f1 = *(const float4*)(xp + kk * 32 + 4);
            s16x8 av;
            av[0] = (short)f2bf(f0.x); av[1] = (short)f2bf(f0.y);
            av[2] = (short)f2bf(f0.z); av[3] = (short)f2bf(f0.w);
            av[4] = (short)f2bf(f1.x); av[5] = (short)f2bf(f1.y);
            av[6] = (short)f2bf(f1.z); av[7] = (short)f2bf(f1.w);
            a[kk] = av;
            *(s16x8*)(xa + (size_t)arow * 256 + kbase + kk * 32) = av;
        }
    } else {
        #pragma unroll
        for (int kk = 0; kk < 4; ++kk) a[kk] = (s16x8)0;
    }

    f32x4 acc[24];
    #pragma unroll
    for (int nt = 0; nt < 24; ++nt) acc[nt] = (f32x4){0.f, 0.f, 0.f, 0.f};

    const s16x8* wfv = (const s16x8*)wf;
    #pragma unroll
    for (int nt = 0; nt < 24; ++nt) {
        #pragma unroll
        for (int kk = 0; kk < 4; ++kk) {
            s16x8 b = wfv[(nt * 4 + kk) * 64 + lane];
            acc[nt] = mfma_bf16(a[kk], b, acc[nt]);
        }
    }

    const int colb = lane & 15;
    const int rbase = row0 + (lane >> 4) * 4;
    #pragma unroll
    for (int nt = 0; nt < 24; ++nt) {
        const int mtx = nt >> 3;                  // 0:Q 1:K 2:V
        const int nc = (nt & 7) * 16 + colb;      // 0..127
        const float* bias_p = (mtx == 0) ? bq : ((mtx == 1) ? bk : bv);
        unsigned short* O = (mtx == 0) ? Qb : ((mtx == 1) ? Kb : Vb);
        float bias = bias_p[nc];
        #pragma unroll
        for (int r = 0; r < 4; ++r)
            O[(size_t)(rbase + r) * 128 + nc] = f2bf(acc[nt][r] + bias);
    }
}

// ---------------- fused per-node attention: 4 nodes per wave ----------------
// score phase: lane = local_edge*4 + head (lane-local 32-dim dot)
// PV phase: half = lane>>5 handles edges of that parity; lane owns dims 4*sl..4*sl+3
__global__ __launch_bounds__(256) void attn_kernel(
        const unsigned short* __restrict__ Qb, const unsigned short* __restrict__ Kb,
        const unsigned short* __restrict__ Vb, const int* __restrict__ rstart,
        const int* __restrict__ colS, unsigned short* __restrict__ xa) {
    const int wave = threadIdx.x >> 6;
    const int lane = threadIdx.x & 63;
    const int h = lane & 3;       // head (score phase)
    const int le = lane >> 2;     // local edge 0..15 (score phase)
    const int half = lane >> 5;   // PV: edge parity
    const int sl = lane & 31;     // PV: dim group (4 dims)
    const int g2 = sl >> 3;       // PV: head of owned dims
    const int ibase = blockIdx.x * 16 + wave * 4;

    for (int j = 0; j < 4; ++j) {
        const int i = ibase + j;   // grid covers exactly NN = 3125*16
        const int e0 = rstart[i], e1 = rstart[i + 1];
        const int deg = e1 - e0;

        // unpack this head's Q slice into 32 f32 regs
        float qf[32];
        {
            const uint4* qp = (const uint4*)(Qb + (size_t)i * 128 + h * 32);
            #pragma unroll
            for (int cch = 0; cch < 4; ++cch) {
                uint4 qv = qp[cch];
                unsigned int w_[4] = {qv.x, qv.y, qv.z, qv.w};
                #pragma unroll
                for (int dd = 0; dd < 4; ++dd) {
                    qf[cch * 8 + dd * 2]     = bflo(w_[dd]);
                    qf[cch * 8 + dd * 2 + 1] = bfhi(w_[dd]);
                }
            }
        }

        float m = -INFINITY, l = 0.f;
        float acc0 = 0.f, acc1 = 0.f, acc2 = 0.f, acc3 = 0.f;

        for (int c0 = 0; c0 < deg; c0 += 16) {
            const int cnt = min(16, deg - c0);
            int col = 0;
            float s = -INFINITY;
            if (le < cnt) {
                col = colS[e0 + c0 + le];
                const uint4* kp = (const uint4*)(Kb + (size_t)col * 128 + h * 32);
                float dot = 0.f;
                #pragma unroll
                for (int cch = 0; cch < 4; ++cch) {
                    uint4 kv = kp[cch];
                    unsigned int w_[4] = {kv.x, kv.y, kv.z, kv.w};
                    #pragma unroll
                    for (int dd = 0; dd < 4; ++dd) {
                        dot += qf[cch * 8 + dd * 2]     * bflo(w_[dd]);
                        dot += qf[cch * 8 + dd * 2 + 1] * bfhi(w_[dd]);
                    }
                }
                s = dot * 0.17677669529663689f;   // 1/sqrt(32)
            }
            // per-head reduce over the 16 edge-lanes (lane stride 4)
            float sm = s;
            sm = fmaxf(sm, __shfl_xor(sm, 4));
            sm = fmaxf(sm, __shfl_xor(sm, 8));
            sm = fmaxf(sm, __shfl_xor(sm, 16));
            sm = fmaxf(sm, __shfl_xor(sm, 32));
            const float mn = fmaxf(m, sm);
            const float p = (le < cnt) ? __expf(s - mn) : 0.f;
            float ps = p;
            ps += __shfl_xor(ps, 4);
            ps += __shfl_xor(ps, 8);
            ps += __shfl_xor(ps, 16);
            ps += __shfl_xor(ps, 32);
            const float fac = __expf(m - mn);   // first chunk: exp(-inf)=0
            l = l * fac + ps;
            m = mn;
            // PV: each half handles 8 edges of its parity; 4 dims per lane (dwordx2)
            const float facbc = __shfl(fac, g2);
            acc0 *= facbc; acc1 *= facbc; acc2 *= facbc; acc3 *= facbc;
            #pragma unroll
            for (int e2 = 0; e2 < 8; ++e2) {
                const int e = 2 * e2 + half;
                const int   cbc = __shfl(col, 4 * e);
                const float pbc = __shfl(p, 4 * e + g2);
                const uint2 v2 = *(const uint2*)(Vb + (size_t)cbc * 128 + 4 * sl);
                acc0 += pbc * bflo(v2.x);
                acc1 += pbc * bfhi(v2.x);
                acc2 += pbc * bflo(v2.y);
                acc3 += pbc * bfhi(v2.y);
            }
        }

        // combine the two edge-parity halves
        acc0 += __shfl_xor(acc0, 32);
        acc1 += __shfl_xor(acc1, 32);
        acc2 += __shfl_xor(acc2, 32);
        acc3 += __shfl_xor(acc3, 32);
        const float lf = __shfl(l, g2);
        const float rinv = (lf > 0.f) ? 1.f / lf : 0.f;
        if (half == 0) {
            uint2 o;
            o.x = ((unsigned int)f2bf(acc1 * rinv) << 16) | (unsigned int)f2bf(acc0 * rinv);
            o.y = ((unsigned int)f2bf(acc3 * rinv) << 16) | (unsigned int)f2bf(acc2 * rinv);
            *(uint2*)(xa + (size_t)i * 256 + 128 + 4 * sl) = o;
        }
    }
}

// ---------------- MLP1 via MFMA + ReLU + LayerNorm -> bf16 h ----------------
__global__ __launch_bounds__(256) void gemm_mlp1_kernel(
        const unsigned short* __restrict__ xa, const unsigned short* __restrict__ w1f,
        const float* __restrict__ b1, const float* __restrict__ ln_g,
        const float* __restrict__ ln_b, unsigned short* __restrict__ hb) {
    const int wave = threadIdx.x >> 6, lane = threadIdx.x & 63;
    const int row0 = blockIdx.x * 64 + wave * 16;
    const int arow = row0 + (lane & 15);

    s16x8 a[8];
    const unsigned short* ap = xa + (size_t)arow * 256 + (lane >> 4) * 8;
    #pragma unroll
    for (int kk = 0; kk < 8; ++kk) a[kk] = *(const s16x8*)(ap + kk * 32);

    f32x4 acc[8];
    #pragma unroll
    for (int nt = 0; nt < 8; ++nt) acc[nt] = (f32x4){0.f, 0.f, 0.f, 0.f};

    const s16x8* wfv = (const s16x8*)w1f;
    #pragma unroll
    for (int nt = 0; nt < 8; ++nt) {
        #pragma unroll
        for (int kk = 0; kk < 8; ++kk) {
            s16x8 b = wfv[(nt * 8 + kk) * 64 + lane];
            acc[nt] = mfma_bf16(a[kk], b, acc[nt]);
        }
    }

    const int colb = lane & 15;
    #pragma unroll
    for (int nt = 0; nt < 8; ++nt) {
        float bias = b1[nt * 16 + colb];
        #pragma unroll
        for (int r = 0; r < 4; ++r) {
            float v = acc[nt][r] + bias;
            acc[nt][r] = v > 0.f ? v : 0.f;
        }
    }
    float mu[4], rs[4];
    #pragma unroll
    for (int r = 0; r < 4; ++r) {
        float s = 0.f, q = 0.f;
        #pragma unroll
        for (int nt = 0; nt < 8; ++nt) { float v = acc[nt][r]; s += v; q += v * v; }
        #pragma unroll
        for (int msk = 1; msk < 16; msk <<= 1) {
            s += __shfl_xor(s, msk, 16);
            q += __shfl_xor(q, msk, 16);
        }
        float m_ = s * (1.f / 128.f);
        float var = q * (1.f / 128.f) - m_ * m_;
        mu[r] = m_;
        rs[r] = rsqrtf(var + LN_EPS);
    }
    const int rbase = row0 + (lane >> 4) * 4;
    #pragma unroll
    for (int nt = 0; nt < 8; ++nt) {
        int col = nt * 16 + colb;
        float g = ln_g[col], bb = ln_b[col];
        #pragma unroll
        for (int r = 0; r < 4; ++r) {
            float h = (acc[nt][r] - mu[r]) * rs[r] * g + bb;
            hb[(size_t)(rbase + r) * 128 + col] = f2bf(h);
        }
    }
}

// ---------------- MLP2 via MFMA + bias + residual (bf16 x from xa) -> f32 out ----------------
__global__ __launch_bounds__(256) void gemm_mlp2_kernel(
        const unsigned short* __restrict__ hb, const unsigned short* __restrict__ w2f,
        const float* __restrict__ b2, const unsigned short* __restrict__ xa,
        float* __restrict__ out) {
    const int wave = threadIdx.x >> 6, lane = threadIdx.x & 63;
    const int row0 = blockIdx.x * 64 + wave * 16;
    const int arow = row0 + (lane & 15);

    s16x8 a[4];
    const unsigned short* ap = hb + (size_t)arow * 128 + (lane >> 4) * 8;
    #pragma unroll
    for (int kk = 0; kk < 4; ++kk) a[kk] = *(const s16x8*)(ap + kk * 32);

    f32x4 acc[8];
    #pragma unroll
    for (int nt = 0; nt < 8; ++nt) acc[nt] = (f32x4){0.f, 0.f, 0.f, 0.f};

    const s16x8* wfv = (const s16x8*)w2f;
    #pragma unroll
    for (int nt = 0; nt < 8; ++nt) {
        #pragma unroll
        for (int kk = 0; kk < 4; ++kk) {
            s16x8 b = wfv[(nt * 4 + kk) * 64 + lane];
            acc[nt] = mfma_bf16(a[kk], b, acc[nt]);
        }
    }

    const int colb = lane & 15;
    const int rbase = row0 + (lane >> 4) * 4;
    #pragma unroll
    for (int nt = 0; nt < 8; ++nt) {
        int col = nt * 16 + colb;
        float bias = b2[col];
        #pragma unroll
        for (int r = 0; r < 4; ++r) {
            int row = rbase + r;
            if (row < NN)
                out[(size_t)row * 128 + col] =
                    acc[nt][r] + bias + bf2f(xa[(size_t)row * 256 + col]);
        }
    }
}

extern "C" void kernel_launch(void* const* d_in, const int* in_sizes, int n_in,
                              void* d_out, int out_size, void* d_ws, size_t ws_size,
                              hipStream_t stream) {
    const float* x    = (const float*)d_in[0];
    const void*  ei   = d_in[1];
    const float* Wq   = (const float*)d_in[2];
    const float* bq   = (const float*)d_in[3];
    const float* Wk   = (const float*)d_in[4];
    const float* bk   = (const float*)d_in[5];
    const float* Wv   = (const float*)d_in[6];
    const float* bv   = (const float*)d_in[7];
    const float* W1   = (const float*)d_in[8];
    const float* b1   = (const float*)d_in[9];
    const float* ln_g = (const float*)d_in[10];
    const float* ln_b = (const float*)d_in[11];
    const float* W2   = (const float*)d_in[12];
    const float* b2   = (const float*)d_in[13];
    float* out = (float*)d_out;

    char* ws = (char*)d_ws;
    size_t off = 0;
    auto alloc = [&](size_t bytes) {
        size_t o = off;
        off = (off + bytes + 255) & ~(size_t)255;
        return o;
    };
    size_t flag_o = alloc(sizeof(int));
    size_t deg_o  = alloc((size_t)NN * sizeof(int));
    size_t rank_o = alloc((size_t)EE * sizeof(int));
    size_t rs_o   = alloc((size_t)(NN + 1) * sizeof(int));
    size_t bsum_o = alloc((size_t)SCAN_NB * sizeof(int));
    size_t colS_o = alloc((size_t)EE * sizeof(int));
    size_t xa_o   = alloc((size_t)ROWS_PAD * 256 * sizeof(unsigned short));
    size_t wf_o   = alloc((size_t)98304 * sizeof(unsigned short));
    size_t Qb_o   = alloc((size_t)ROWS_PAD * 128 * sizeof(unsigned short));
    size_t Kb_o   = alloc((size_t)ROWS_PAD * 128 * sizeof(unsigned short));
    size_t Vb_o   = alloc((size_t)ROWS_PAD * 128 * sizeof(unsigned short));
    size_t hb_o   = Qb_o;  // h reuses Q (dead after attn)

    int* flag   = (int*)(ws + flag_o);
    int* deg    = (int*)(ws + deg_o);
    int* rank   = (int*)(ws + rank_o);
    int* rstart = (int*)(ws + rs_o);
    int* bsum   = (int*)(ws + bsum_o);
    int* colS   = (int*)(ws + colS_o);
    unsigned short* xa = (unsigned short*)(ws + xa_o);
    unsigned short* wf = (unsigned short*)(ws + wf_o);
    unsigned short* Qb = (unsigned short*)(ws + Qb_o);
    unsigned short* Kb = (unsigned short*)(ws + Kb_o);
    unsigned short* Vb = (unsigned short*)(ws + Vb_o);
    unsigned short* hb = (unsigned short*)(ws + hb_o);

    hipMemsetAsync(ws + deg_o, 0, (size_t)NN * sizeof(int), stream);

    detect_idx_kernel<<<1, 64, 0, stream>>>((const unsigned int*)ei, flag);
    hist_kernel<<<(EE / 2 + 255) / 256, 256, 0, stream>>>(ei, flag, deg, rank);
    scan_a_kernel<<<SCAN_NB, 512, 0, stream>>>(deg, bsum);
    scan_c_kernel<<<SCAN_NB, 512, 0, stream>>>(deg, bsum, rstart);
    scatter_kernel<<<(EE / 2 + 255) / 256, 256, 0, stream>>>(ei, flag, rank, rstart, colS);

    pack_w_kernel<<<98304 / 256, 256, 0, stream>>>(Wq, Wk, Wv, W1, W2, wf);

    qkvx_kernel<<<ROWS_PAD / 64, 256, 0, stream>>>(x, wf, bq, bk, bv, xa, Qb, Kb, Vb);

    attn_kernel<<<NN / 16, 256, 0, stream>>>(Qb, Kb, Vb, rstart, colS, xa);

    gemm_mlp1_kernel<<<ROWS_PAD / 64, 256, 0, stream>>>(xa, wf + 49152, b1, ln_g, ln_b, hb);

    gemm_mlp2_kernel<<<ROWS_PAD / 64, 256, 0, stream>>>(hb, wf + 81920, b2, xa, out);
}